// Round 1
// baseline (1629.131 us; speedup 1.0000x reference)
//
#include <hip/hip_runtime.h>
#include <math.h>

#define NH 16
#define DPH 64
#define SLEN 2048
#define BSZ 2
#define DIM 1024
#define NTOK (BSZ * SLEN)

// ---------------------------------------------------------------------------
// GEMM: out = A(M x K) @ W(K x N) + bias ; M=NTOK, K=N=DIM.
// PERMUTE=1: write out in (b, h, t, d) head-major layout for attention.
// fp32 baseline: 64x64 tile, A transposed in LDS so both operand reads are
// ds_read_b128. 4x4 accumulators per thread.
// ---------------------------------------------------------------------------
template <int PERMUTE>
__global__ __launch_bounds__(256) void gemm_bias(const float* __restrict__ A,
                                                 const float* __restrict__ W,
                                                 const float* __restrict__ bias,
                                                 float* __restrict__ out) {
    __shared__ float AsT[64][68];  // [k][row], +4 pad keeps 16B align, spreads banks
    __shared__ float Ws[64][68];   // [k][col]
    const int tid = threadIdx.x;
    const int tx = tid & 15;       // col group
    const int ty = tid >> 4;       // row group
    const int col0 = blockIdx.x * 64;
    const int row0 = blockIdx.y * 64;
    float acc[4][4] = {};

    for (int kc = 0; kc < DIM; kc += 64) {
        __syncthreads();
#pragma unroll
        for (int p = 0; p < 4; p++) {
            int lin = p * 256 + tid;
            int r = lin >> 4;
            int c4 = (lin & 15) * 4;
            float4 a4 = *(const float4*)&A[(size_t)(row0 + r) * DIM + kc + c4];
            AsT[c4 + 0][r] = a4.x;
            AsT[c4 + 1][r] = a4.y;
            AsT[c4 + 2][r] = a4.z;
            AsT[c4 + 3][r] = a4.w;
            float4 w4 = *(const float4*)&W[(size_t)(kc + r) * DIM + col0 + c4];
            *(float4*)&Ws[r][c4] = w4;
        }
        __syncthreads();
#pragma unroll
        for (int kk = 0; kk < 64; kk++) {
            float4 a = *(const float4*)&AsT[kk][ty * 4];
            float4 b = *(const float4*)&Ws[kk][tx * 4];
            float av[4] = {a.x, a.y, a.z, a.w};
            float bv[4] = {b.x, b.y, b.z, b.w};
#pragma unroll
            for (int i = 0; i < 4; i++)
#pragma unroll
                for (int j = 0; j < 4; j++) acc[i][j] += av[i] * bv[j];
        }
    }

    float4 bvec = *(const float4*)&bias[col0 + tx * 4];
    float bb[4] = {bvec.x, bvec.y, bvec.z, bvec.w};
#pragma unroll
    for (int i = 0; i < 4; i++) {
        int r = row0 + ty * 4 + i;
        float4 o;
        o.x = acc[i][0] + bb[0];
        o.y = acc[i][1] + bb[1];
        o.z = acc[i][2] + bb[2];
        o.w = acc[i][3] + bb[3];
        if (PERMUTE) {
            int bidx = r >> 11;         // r / SLEN
            int t = r & (SLEN - 1);
            int c = col0 + tx * 4;
            int h = c >> 6;
            int d = c & 63;
            *(float4*)&out[((size_t)(bidx * NH + h) * SLEN + t) * DPH + d] = o;
        } else {
            *(float4*)&out[(size_t)r * DIM + col0 + tx * 4] = o;
        }
    }
}

// ---------------------------------------------------------------------------
// L2-normalize rows of 64 (one wave per row); optional attention_scale.
// ---------------------------------------------------------------------------
__global__ __launch_bounds__(256) void l2norm(float* __restrict__ X,
                                              const float* __restrict__ scale,
                                              int apply) {
    const int lane = threadIdx.x & 63;
    const int row = blockIdx.x * 4 + (threadIdx.x >> 6);
    float v = X[(size_t)row * DPH + lane];
    float ss = v * v;
#pragma unroll
    for (int o = 32; o > 0; o >>= 1) ss += __shfl_xor(ss, o);
    float sc = 1.0f / fmaxf(sqrtf(ss), 1e-12f);
    if (apply) sc *= scale[0];
    X[(size_t)row * DPH + lane] = v * sc;
}

// ---------------------------------------------------------------------------
// Causal flash attention, fp32.
// Q,K,V: [BSZ*NH][SLEN][64] head-major. O: [BSZ][SLEN][NH][64] token-major.
// Block = 256 thr (4 waves), 64 q-rows per block (16 per wave), key tiles of 64.
// K/V in LDS with XOR swizzle c^(r&31): lane-indexed row (K) and column (V)
// scalar reads are bank-conflict-free. Q/P reads are wave-uniform broadcasts.
// LDS = 4 * 64*64*4B = 64 KiB exactly.
// ---------------------------------------------------------------------------
__global__ __launch_bounds__(256) void flash_attn(const float* __restrict__ Q,
                                                  const float* __restrict__ K,
                                                  const float* __restrict__ V,
                                                  float* __restrict__ O) {
    __shared__ float Qs[64][64];
    __shared__ float Ks[64][64];
    __shared__ float Vs[64][64];
    __shared__ float Ps[64][64];

    const int tid = threadIdx.x;
    const int lane = tid & 63;
    const int wid = tid >> 6;
    const int r0 = wid * 16;
    const int qt = blockIdx.x;  // query tile 0..31
    const int bh = blockIdx.y;  // 0..31
    const size_t base = (size_t)bh * SLEN * DPH;
    const int sw = lane & 31;

    // stage Q tile (plain layout; only read via uniform broadcast)
#pragma unroll
    for (int p = 0; p < 4; p++) {
        int lin = p * 256 + tid;
        int r = lin >> 4;
        int c4 = (lin & 15) * 4;
        *(float4*)&Qs[r][c4] =
            *(const float4*)&Q[base + (size_t)(qt * 64 + r) * DPH + c4];
    }

    float m[16], l[16], acc[16], s[16];
#pragma unroll
    for (int i = 0; i < 16; i++) {
        m[i] = -INFINITY;
        l[i] = 0.f;
        acc[i] = 0.f;
    }

    for (int kb = 0; kb <= qt; kb++) {
        __syncthreads();  // protect Ks/Vs from previous iteration's readers
#pragma unroll
        for (int p = 0; p < 4; p++) {
            int lin = p * 256 + tid;
            int r = lin >> 4;
            int c4 = (lin & 15) * 4;
            int rs = r & 31;
            float4 k4 = *(const float4*)&K[base + (size_t)(kb * 64 + r) * DPH + c4];
            Ks[r][(c4 + 0) ^ rs] = k4.x;
            Ks[r][(c4 + 1) ^ rs] = k4.y;
            Ks[r][(c4 + 2) ^ rs] = k4.z;
            Ks[r][(c4 + 3) ^ rs] = k4.w;
            float4 v4 = *(const float4*)&V[base + (size_t)(kb * 64 + r) * DPH + c4];
            Vs[r][(c4 + 0) ^ rs] = v4.x;
            Vs[r][(c4 + 1) ^ rs] = v4.y;
            Vs[r][(c4 + 2) ^ rs] = v4.z;
            Vs[r][(c4 + 3) ^ rs] = v4.w;
        }
        __syncthreads();

        // S = Q K^T, lane = key index
#pragma unroll
        for (int i = 0; i < 16; i++) s[i] = 0.f;
        for (int d4 = 0; d4 < 64; d4 += 4) {
            float k0 = Ks[lane][(d4 + 0) ^ sw];
            float k1 = Ks[lane][(d4 + 1) ^ sw];
            float k2 = Ks[lane][(d4 + 2) ^ sw];
            float k3 = Ks[lane][(d4 + 3) ^ sw];
#pragma unroll
            for (int qr = 0; qr < 16; qr++) {
                const float4 q4 = *(const float4*)&Qs[r0 + qr][d4];
                s[qr] += q4.x * k0 + q4.y * k1 + q4.z * k2 + q4.w * k3;
            }
        }

        if (kb == qt) {  // diagonal block: causal mask
#pragma unroll
            for (int qr = 0; qr < 16; qr++)
                if (lane > r0 + qr) s[qr] = -INFINITY;
        }

        // online softmax (per q-row over 64 lanes = keys)
#pragma unroll
        for (int qr = 0; qr < 16; qr++) {
            float mb = s[qr];
#pragma unroll
            for (int o = 32; o > 0; o >>= 1) mb = fmaxf(mb, __shfl_xor(mb, o));
            float mn = fmaxf(m[qr], mb);
            float scal = (m[qr] == -INFINITY) ? 0.f : __expf(m[qr] - mn);
            float p = __expf(s[qr] - mn);
            float rsum = p;
#pragma unroll
            for (int o = 32; o > 0; o >>= 1) rsum += __shfl_xor(rsum, o);
            l[qr] = l[qr] * scal + rsum;
            acc[qr] *= scal;
            m[qr] = mn;
            Ps[r0 + qr][lane] = p;  // wave-private rows: no barrier needed
        }

        // PV: lane = output dim
        for (int k4 = 0; k4 < 64; k4 += 4) {
            float v0 = Vs[k4 + 0][lane ^ ((k4 + 0) & 31)];
            float v1 = Vs[k4 + 1][lane ^ ((k4 + 1) & 31)];
            float v2 = Vs[k4 + 2][lane ^ ((k4 + 2) & 31)];
            float v3 = Vs[k4 + 3][lane ^ ((k4 + 3) & 31)];
#pragma unroll
            for (int qr = 0; qr < 16; qr++) {
                const float4 p4 = *(const float4*)&Ps[r0 + qr][k4];
                acc[qr] += p4.x * v0 + p4.y * v1 + p4.z * v2 + p4.w * v3;
            }
        }
    }

    // write ctx token-major (b, t, h, d) so O-proj is a plain GEMM
    const int b = bh >> 4;
    const int h = bh & 15;
#pragma unroll
    for (int qr = 0; qr < 16; qr++) {
        int t = qt * 64 + r0 + qr;
        O[((size_t)(b * SLEN + t) * NH + h) * DPH + lane] = acc[qr] / l[qr];
    }
}

// ---------------------------------------------------------------------------
// inputs: 0 x, 1 mask (unused; deterministically causal), 2 Wq, 3 bq, 4 Wk,
// 5 bk, 6 Wv, 7 bv, 8 Wo, 9 bo, 10 attention_scale
// ---------------------------------------------------------------------------
extern "C" void kernel_launch(void* const* d_in, const int* in_sizes, int n_in,
                              void* d_out, int out_size, void* d_ws,
                              size_t ws_size, hipStream_t stream) {
    const float* x = (const float*)d_in[0];
    const float* Wq = (const float*)d_in[2];
    const float* bq = (const float*)d_in[3];
    const float* Wk = (const float*)d_in[4];
    const float* bk = (const float*)d_in[5];
    const float* Wv = (const float*)d_in[6];
    const float* bv = (const float*)d_in[7];
    const float* Wo = (const float*)d_in[8];
    const float* bo = (const float*)d_in[9];
    const float* ascale = (const float*)d_in[10];
    float* out = (float*)d_out;

    const size_t NELT = (size_t)NTOK * DIM;  // 4M floats, 16 MB
    float* Qb = out;  // d_out doubles as Q scratch; fully overwritten at the end
    float* Kb = (float*)d_ws;
    float* Vb = Kb + NELT;
    float* Cb = Vb + NELT;  // ws usage: 48 MB

    dim3 gg(DIM / 64, NTOK / 64);
    dim3 gb(256);
    gemm_bias<1><<<gg, gb, 0, stream>>>(x, Wq, bq, Qb);
    gemm_bias<1><<<gg, gb, 0, stream>>>(x, Wk, bk, Kb);
    gemm_bias<1><<<gg, gb, 0, stream>>>(x, Wv, bv, Vb);

    l2norm<<<(BSZ * NH * SLEN) / 4, 256, 0, stream>>>(Qb, ascale, 1);
    l2norm<<<(BSZ * NH * SLEN) / 4, 256, 0, stream>>>(Kb, ascale, 0);

    flash_attn<<<dim3(SLEN / 64, BSZ * NH), 256, 0, stream>>>(Qb, Kb, Vb, Cb);

    gemm_bias<0><<<gg, gb, 0, stream>>>(Cb, Wo, bo, out);
}

// Round 2
// 210.714 us; speedup vs baseline: 7.7315x; 7.7315x over previous
//
#include <hip/hip_runtime.h>
#include <math.h>

#define NH 16
#define DPH 64
#define SLEN 2048
#define BSZ 2
#define DIM 1024
#define NTOK (BSZ * SLEN)

typedef unsigned short ushortT;
typedef __attribute__((ext_vector_type(8))) short short8;
typedef __attribute__((ext_vector_type(4))) float f32x4;

__device__ __forceinline__ ushortT f2bf(float f) {
    unsigned int u = __builtin_bit_cast(unsigned int, f);
    u = u + 0x7fffu + ((u >> 16) & 1u);  // RNE
    return (ushortT)(u >> 16);
}

// ---------------------------------------------------------------------------
// x (fp32) -> bf16, 8 elems/thread
// ---------------------------------------------------------------------------
__global__ __launch_bounds__(256) void cvt_x(const float* __restrict__ x,
                                             ushortT* __restrict__ xb) {
    size_t i = (size_t)blockIdx.x * 256 + threadIdx.x;
    float4 a = *(const float4*)&x[i * 8];
    float4 b = *(const float4*)&x[i * 8 + 4];
    short8 v;
    v[0] = (short)f2bf(a.x); v[1] = (short)f2bf(a.y);
    v[2] = (short)f2bf(a.z); v[3] = (short)f2bf(a.w);
    v[4] = (short)f2bf(b.x); v[5] = (short)f2bf(b.y);
    v[6] = (short)f2bf(b.z); v[7] = (short)f2bf(b.w);
    *(short8*)&xb[i * 8] = v;
}

// ---------------------------------------------------------------------------
// W[k][n] fp32 -> Wt[n][k] bf16 (transpose + convert), 64x64 tiles
// ---------------------------------------------------------------------------
__global__ __launch_bounds__(256) void cvt_wt(const float* __restrict__ W0, const float* __restrict__ W1,
                                              const float* __restrict__ W2, const float* __restrict__ W3,
                                              ushortT* __restrict__ T0, ushortT* __restrict__ T1,
                                              ushortT* __restrict__ T2, ushortT* __restrict__ T3) {
    const float* W = blockIdx.z == 0 ? W0 : blockIdx.z == 1 ? W1 : blockIdx.z == 2 ? W2 : W3;
    ushortT* T = blockIdx.z == 0 ? T0 : blockIdx.z == 1 ? T1 : blockIdx.z == 2 ? T2 : T3;
    __shared__ float tile[64][65];
    const int tid = threadIdx.x;
    const int kb = blockIdx.y * 64, nb = blockIdx.x * 64;
#pragma unroll
    for (int it = 0; it < 4; it++) {
        int chunk = it * 256 + tid;
        int r = chunk >> 4, c4 = (chunk & 15) * 4;
        *(float4*)&tile[r][c4] = *(const float4*)&W[(size_t)(kb + r) * DIM + nb + c4];
    }
    __syncthreads();
#pragma unroll
    for (int it = 0; it < 2; it++) {
        int chunk = it * 256 + tid;
        int n = chunk >> 3, k8 = (chunk & 7) * 8;
        short8 o;
#pragma unroll
        for (int j = 0; j < 8; j++) o[j] = (short)f2bf(tile[k8 + j][n]);
        *(short8*)&T[(size_t)(nb + n) * DIM + kb + k8] = o;
    }
}

// ---------------------------------------------------------------------------
// bf16 MFMA GEMM: C = A(M,K) @ Bt(N,K)^T + bias. 128x128 tile, BK=64,
// 4 waves (2x2), 4x4 16x16 frags/wave. LDS XOR-swizzled (row&7) both sides.
// MODE 0: fp32 plain [M][N]. MODE 1: fp32 head-major. MODE 2: bf16 head-major.
// ---------------------------------------------------------------------------
template <int MODE>
__global__ __launch_bounds__(256) void gemm_bf16(const ushortT* __restrict__ A,
                                                 const ushortT* __restrict__ Bt,
                                                 const float* __restrict__ bias,
                                                 float* __restrict__ outF,
                                                 ushortT* __restrict__ outH) {
    __shared__ __align__(16) ushortT As[128 * 64];
    __shared__ __align__(16) ushortT Bs[128 * 64];
    const int tid = threadIdx.x;
    const int lane = tid & 63, wid = tid >> 6;
    const int wr = wid >> 1, wc = wid & 1;
    const int row0 = blockIdx.y * 128, col0 = blockIdx.x * 128;
    f32x4 acc[4][4] = {};

    for (int kc = 0; kc < DIM; kc += 64) {
        __syncthreads();
#pragma unroll
        for (int it = 0; it < 4; it++) {
            int chunk = it * 256 + tid;
            int r = chunk >> 3, s = chunk & 7;
            int lo = r * 64 + ((s ^ (r & 7)) << 3);
            *(uint4*)&As[lo] = *(const uint4*)&A[(size_t)(row0 + r) * DIM + kc + s * 8];
            *(uint4*)&Bs[lo] = *(const uint4*)&Bt[(size_t)(col0 + r) * DIM + kc + s * 8];
        }
        __syncthreads();
#pragma unroll
        for (int ks = 0; ks < 2; ks++) {
            short8 af[4], bf[4];
#pragma unroll
            for (int m = 0; m < 4; m++) {
                int row = wr * 64 + m * 16 + (lane & 15);
                af[m] = *(const short8*)&As[row * 64 + (((ks * 4 + (lane >> 4)) ^ (row & 7)) << 3)];
            }
#pragma unroll
            for (int n = 0; n < 4; n++) {
                int row = wc * 64 + n * 16 + (lane & 15);
                bf[n] = *(const short8*)&Bs[row * 64 + (((ks * 4 + (lane >> 4)) ^ (row & 7)) << 3)];
            }
#pragma unroll
            for (int m = 0; m < 4; m++)
#pragma unroll
                for (int n = 0; n < 4; n++)
                    acc[m][n] = __builtin_amdgcn_mfma_f32_16x16x32_bf16(af[m], bf[n], acc[m][n], 0, 0, 0);
        }
    }
#pragma unroll
    for (int n = 0; n < 4; n++) {
        int c = col0 + wc * 64 + n * 16 + (lane & 15);
        float bv = bias[c];
#pragma unroll
        for (int m = 0; m < 4; m++)
#pragma unroll
            for (int r = 0; r < 4; r++) {
                int rg = row0 + wr * 64 + m * 16 + (lane >> 4) * 4 + r;
                float v = acc[m][n][r] + bv;
                if (MODE == 0) {
                    outF[(size_t)rg * DIM + c] = v;
                } else {
                    int b = rg >> 11, t = rg & (SLEN - 1);
                    int h = c >> 6, d = c & 63;
                    size_t idx = ((size_t)(b * NH + h) * SLEN + t) * DPH + d;
                    if (MODE == 1) outF[idx] = v;
                    else outH[idx] = f2bf(v);
                }
            }
    }
}

// ---------------------------------------------------------------------------
// L2-normalize rows of 64 (fp32 in, bf16 out), optional attention_scale.
// ---------------------------------------------------------------------------
__global__ __launch_bounds__(256) void l2norm_bf(const float* __restrict__ X,
                                                 ushortT* __restrict__ Y,
                                                 const float* __restrict__ scale,
                                                 int apply) {
    const int lane = threadIdx.x & 63;
    const size_t row = (size_t)blockIdx.x * 4 + (threadIdx.x >> 6);
    float v = X[row * DPH + lane];
    float ss = v * v;
#pragma unroll
    for (int o = 32; o > 0; o >>= 1) ss += __shfl_xor(ss, o);
    float sc = 1.0f / fmaxf(sqrtf(ss), 1e-12f);
    if (apply) sc *= scale[0];
    Y[row * DPH + lane] = f2bf(v * sc);
}

// ---------------------------------------------------------------------------
// V[bh][t][64] bf16 -> Vt[bh][64][2048] bf16 (64x64 tiles via LDS)
// ---------------------------------------------------------------------------
__global__ __launch_bounds__(256) void vtrans(const ushortT* __restrict__ Vh,
                                              ushortT* __restrict__ Vt) {
    __shared__ ushortT tile[64][66];
    const int tid = threadIdx.x;
    const int bh = blockIdx.x, kb = blockIdx.y;
    const size_t base = (size_t)bh * SLEN * DPH;
#pragma unroll
    for (int it = 0; it < 2; it++) {
        int chunk = it * 256 + tid;
        int t = chunk >> 3, c8 = (chunk & 7) * 8;
        short8 v = *(const short8*)&Vh[base + (size_t)(kb * 64 + t) * DPH + c8];
#pragma unroll
        for (int j = 0; j < 8; j++) tile[t][c8 + j] = (ushortT)v[j];
    }
    __syncthreads();
#pragma unroll
    for (int it = 0; it < 2; it++) {
        int chunk = it * 256 + tid;
        int d = chunk >> 3, t8 = (chunk & 7) * 8;
        short8 o;
#pragma unroll
        for (int j = 0; j < 8; j++) o[j] = (short)tile[t8 + j][d];
        *(short8*)&Vt[base + (size_t)d * SLEN + kb * 64 + t8] = o;
    }
}

// ---------------------------------------------------------------------------
// Causal flash attention, bf16 MFMA 16x16x32.
// Q,K: [bh][2048][64] bf16; Vt: [bh][64][2048] bf16; ctx: [b][t][h*64+d] bf16.
// 256 thr = 4 waves x 16 q-rows; key tiles of 64; online softmax per C-frag
// row group (16-lane shfl). All LDS tiles XOR-swizzled by (row&7).
// ---------------------------------------------------------------------------
__global__ __launch_bounds__(256) void attn(const ushortT* __restrict__ Q,
                                            const ushortT* __restrict__ K,
                                            const ushortT* __restrict__ Vt,
                                            ushortT* __restrict__ ctx) {
    __shared__ __align__(16) ushortT Qs[64 * 64];
    __shared__ __align__(16) ushortT Ks[64 * 64];
    __shared__ __align__(16) ushortT Vs[64 * 64];
    __shared__ __align__(16) ushortT Ps[4 * 16 * 64];
    const int tid = threadIdx.x, lane = tid & 63, wid = tid >> 6;
    const int bh = blockIdx.x, qt = blockIdx.y;
    const size_t hb = (size_t)bh * SLEN * DPH;

#pragma unroll
    for (int it = 0; it < 2; it++) {
        int chunk = it * 256 + tid;
        int r = chunk >> 3, s = chunk & 7;
        *(uint4*)&Qs[r * 64 + ((s ^ (r & 7)) << 3)] =
            *(const uint4*)&Q[hb + (size_t)(qt * 64 + r) * DPH + s * 8];
    }
    __syncthreads();
    short8 aq[2];
    {
        int row = wid * 16 + (lane & 15);
#pragma unroll
        for (int ks = 0; ks < 2; ks++)
            aq[ks] = *(const short8*)&Qs[row * 64 + (((ks * 4 + (lane >> 4)) ^ (row & 7)) << 3)];
    }

    f32x4 accd[4] = {};
    float mrun[4], lrun[4];
#pragma unroll
    for (int r = 0; r < 4; r++) { mrun[r] = -INFINITY; lrun[r] = 0.f; }

    for (int kb = 0; kb <= qt; kb++) {
        __syncthreads();
#pragma unroll
        for (int it = 0; it < 2; it++) {
            int chunk = it * 256 + tid;
            int r = chunk >> 3, s = chunk & 7;
            int lo = r * 64 + ((s ^ (r & 7)) << 3);
            *(uint4*)&Ks[lo] = *(const uint4*)&K[hb + (size_t)(kb * 64 + r) * DPH + s * 8];
            *(uint4*)&Vs[lo] = *(const uint4*)&Vt[hb + (size_t)r * SLEN + kb * 64 + s * 8];
        }
        __syncthreads();

        f32x4 sf[4] = {};
#pragma unroll
        for (int ks = 0; ks < 2; ks++)
#pragma unroll
            for (int j = 0; j < 4; j++) {
                int row = j * 16 + (lane & 15);
                short8 bk = *(const short8*)&Ks[row * 64 + (((ks * 4 + (lane >> 4)) ^ (row & 7)) << 3)];
                sf[j] = __builtin_amdgcn_mfma_f32_16x16x32_bf16(aq[ks], bk, sf[j], 0, 0, 0);
            }

        if (kb == qt) {
#pragma unroll
            for (int j = 0; j < 4; j++)
#pragma unroll
                for (int r = 0; r < 4; r++) {
                    int keyl = j * 16 + (lane & 15);
                    int ql = wid * 16 + (lane >> 4) * 4 + r;
                    if (keyl > ql) sf[j][r] = -INFINITY;
                }
        }

#pragma unroll
        for (int r = 0; r < 4; r++) {
            float mt = fmaxf(fmaxf(sf[0][r], sf[1][r]), fmaxf(sf[2][r], sf[3][r]));
#pragma unroll
            for (int o = 8; o > 0; o >>= 1) mt = fmaxf(mt, __shfl_xor(mt, o));
            float mn = fmaxf(mrun[r], mt);
            float sc = __expf(mrun[r] - mn);  // -inf on first tile -> 0
            float p[4], rs = 0.f;
#pragma unroll
            for (int j = 0; j < 4; j++) { p[j] = __expf(sf[j][r] - mn); rs += p[j]; }
#pragma unroll
            for (int o = 8; o > 0; o >>= 1) rs += __shfl_xor(rs, o);
            lrun[r] = lrun[r] * sc + rs;
            mrun[r] = mn;
#pragma unroll
            for (int jd = 0; jd < 4; jd++) accd[jd][r] *= sc;
            int prow = (lane >> 4) * 4 + r;
#pragma unroll
            for (int j = 0; j < 4; j++) {
                int col = j * 16 + (lane & 15);
                Ps[(wid * 16 + prow) * 64 + (((col >> 3) ^ (prow & 7)) << 3) + (col & 7)] =
                    f2bf(p[j]);
            }
        }

#pragma unroll
        for (int ks = 0; ks < 2; ks++) {
            int prow = lane & 15;
            short8 ap = *(const short8*)&Ps[(wid * 16 + prow) * 64 +
                                            (((ks * 4 + (lane >> 4)) ^ (prow & 7)) << 3)];
#pragma unroll
            for (int jd = 0; jd < 4; jd++) {
                int drow = jd * 16 + (lane & 15);
                short8 bv = *(const short8*)&Vs[drow * 64 +
                                                (((ks * 4 + (lane >> 4)) ^ (drow & 7)) << 3)];
                accd[jd] = __builtin_amdgcn_mfma_f32_16x16x32_bf16(ap, bv, accd[jd], 0, 0, 0);
            }
        }
    }

    const int b = bh >> 4, h = bh & 15;
#pragma unroll
    for (int jd = 0; jd < 4; jd++)
#pragma unroll
        for (int r = 0; r < 4; r++) {
            int ql = wid * 16 + (lane >> 4) * 4 + r;
            int t = qt * 64 + ql;
            int d = jd * 16 + (lane & 15);
            ctx[(size_t)(b * SLEN + t) * DIM + h * 64 + d] = f2bf(accd[jd][r] / lrun[r]);
        }
}

// ---------------------------------------------------------------------------
// inputs: 0 x, 1 mask(unused), 2 Wq, 3 bq, 4 Wk, 5 bk, 6 Wv, 7 bv, 8 Wo,
// 9 bo, 10 attention_scale
// ---------------------------------------------------------------------------
extern "C" void kernel_launch(void* const* d_in, const int* in_sizes, int n_in,
                              void* d_out, int out_size, void* d_ws,
                              size_t ws_size, hipStream_t stream) {
    const float* x = (const float*)d_in[0];
    const float* Wq = (const float*)d_in[2];
    const float* bq = (const float*)d_in[3];
    const float* Wk = (const float*)d_in[4];
    const float* bk = (const float*)d_in[5];
    const float* Wv = (const float*)d_in[6];
    const float* bv = (const float*)d_in[7];
    const float* Wo = (const float*)d_in[8];
    const float* bo = (const float*)d_in[9];
    const float* ascale = (const float*)d_in[10];
    float* outF = (float*)d_out;  // doubles as Q/K fp32 head-major scratch

    unsigned char* ws = (unsigned char*)d_ws;
    const size_t MB = 1u << 20;
    ushortT* xb = (ushortT*)(ws);              // 8 MB; dead after V GEMM
    ushortT* VtB = (ushortT*)(ws);             // aliases xb
    ushortT* Wqt = (ushortT*)(ws + 8 * MB);
    ushortT* Wkt = (ushortT*)(ws + 10 * MB);
    ushortT* Wvt = (ushortT*)(ws + 12 * MB);
    ushortT* Wot = (ushortT*)(ws + 14 * MB);
    ushortT* Qb = (ushortT*)(ws + 16 * MB);
    ushortT* Kb = (ushortT*)(ws + 24 * MB);
    ushortT* Vb = (ushortT*)(ws + 32 * MB);
    ushortT* ctxb = (ushortT*)(ws + 40 * MB);  // total 48 MB

    cvt_x<<<NTOK * DIM / (8 * 256), 256, 0, stream>>>(x, xb);
    cvt_wt<<<dim3(16, 16, 4), 256, 0, stream>>>(Wq, Wk, Wv, Wo, Wqt, Wkt, Wvt, Wot);

    dim3 gg(DIM / 128, NTOK / 128);
    gemm_bf16<1><<<gg, 256, 0, stream>>>(xb, Wqt, bq, outF, nullptr);
    l2norm_bf<<<BSZ * NH * SLEN / 4, 256, 0, stream>>>(outF, Qb, ascale, 1);
    gemm_bf16<1><<<gg, 256, 0, stream>>>(xb, Wkt, bk, outF, nullptr);
    l2norm_bf<<<BSZ * NH * SLEN / 4, 256, 0, stream>>>(outF, Kb, ascale, 0);
    gemm_bf16<2><<<gg, 256, 0, stream>>>(xb, Wvt, bv, nullptr, Vb);
    vtrans<<<dim3(32, 32), 256, 0, stream>>>(Vb, VtB);

    attn<<<dim3(32, 32), 256, 0, stream>>>(Qb, Kb, VtB, ctxb);

    gemm_bf16<0><<<gg, 256, 0, stream>>>(ctxb, Wot, bo, outF, nullptr);
}

// Round 3
// 171.627 us; speedup vs baseline: 9.4923x; 1.2277x over previous
//
#include <hip/hip_runtime.h>
#include <math.h>

#define NH 16
#define DPH 64
#define SLEN 2048
#define BSZ 2
#define DIM 1024
#define NTOK (BSZ * SLEN)

typedef unsigned short ushortT;
typedef __attribute__((ext_vector_type(8))) short short8;
typedef __attribute__((ext_vector_type(4))) float f32x4;

typedef __attribute__((address_space(1))) const unsigned int gu32c;
typedef __attribute__((address_space(3))) unsigned int lu32;

__device__ __forceinline__ void gld16(const void* g, void* l) {
    __builtin_amdgcn_global_load_lds((gu32c*)g, (lu32*)l, 16, 0, 0);
}

__device__ __forceinline__ ushortT f2bf(float f) {
    unsigned int u = __builtin_bit_cast(unsigned int, f);
    u = u + 0x7fffu + ((u >> 16) & 1u);  // RNE
    return (ushortT)(u >> 16);
}

// ---------------------------------------------------------------------------
// x (fp32) -> bf16, 8 elems/thread
// ---------------------------------------------------------------------------
__global__ __launch_bounds__(256) void cvt_x(const float* __restrict__ x,
                                             ushortT* __restrict__ xb) {
    size_t i = (size_t)blockIdx.x * 256 + threadIdx.x;
    float4 a = *(const float4*)&x[i * 8];
    float4 b = *(const float4*)&x[i * 8 + 4];
    short8 v;
    v[0] = (short)f2bf(a.x); v[1] = (short)f2bf(a.y);
    v[2] = (short)f2bf(a.z); v[3] = (short)f2bf(a.w);
    v[4] = (short)f2bf(b.x); v[5] = (short)f2bf(b.y);
    v[6] = (short)f2bf(b.z); v[7] = (short)f2bf(b.w);
    *(short8*)&xb[i * 8] = v;
}

// ---------------------------------------------------------------------------
// W[k][n] fp32 -> Wt[n][k] bf16 (transpose + convert), 64x64 tiles
// ---------------------------------------------------------------------------
__global__ __launch_bounds__(256) void cvt_wt(const float* __restrict__ W0, const float* __restrict__ W1,
                                              const float* __restrict__ W2, const float* __restrict__ W3,
                                              ushortT* __restrict__ T0, ushortT* __restrict__ T1,
                                              ushortT* __restrict__ T2, ushortT* __restrict__ T3) {
    const float* W = blockIdx.z == 0 ? W0 : blockIdx.z == 1 ? W1 : blockIdx.z == 2 ? W2 : W3;
    ushortT* T = blockIdx.z == 0 ? T0 : blockIdx.z == 1 ? T1 : blockIdx.z == 2 ? T2 : T3;
    __shared__ float tile[64][65];
    const int tid = threadIdx.x;
    const int kb = blockIdx.y * 64, nb = blockIdx.x * 64;
#pragma unroll
    for (int it = 0; it < 4; it++) {
        int chunk = it * 256 + tid;
        int r = chunk >> 4, c4 = (chunk & 15) * 4;
        *(float4*)&tile[r][c4] = *(const float4*)&W[(size_t)(kb + r) * DIM + nb + c4];
    }
    __syncthreads();
#pragma unroll
    for (int it = 0; it < 2; it++) {
        int chunk = it * 256 + tid;
        int n = chunk >> 3, k8 = (chunk & 7) * 8;
        short8 o;
#pragma unroll
        for (int j = 0; j < 8; j++) o[j] = (short)f2bf(tile[k8 + j][n]);
        *(short8*)&T[(size_t)(nb + n) * DIM + kb + k8] = o;
    }
}

// ---------------------------------------------------------------------------
// bf16 MFMA GEMM, 128x128 tile, BK=64, global_load_lds staging with
// pre-swizzled source (linear LDS dest, chunk s at slot s^(r&7)).
// MODE 0: fp32 [M][1024] + b0 -> outF            (O-projection)
// MODE 1: fused QKV (N=3072). which=col0>>10 selects {bias, out}; Q/K rows
//         L2-normalized in-register (fp32 accum), Q scaled by ascale;
//         writes bf16 head-major [b,h,t,d].
// ---------------------------------------------------------------------------
template <int MODE>
__global__ __launch_bounds__(256) void gemm_bf16(const ushortT* __restrict__ A,
                                                 const ushortT* __restrict__ Bt,
                                                 const float* __restrict__ b0,
                                                 const float* __restrict__ b1,
                                                 const float* __restrict__ b2,
                                                 const float* __restrict__ ascale,
                                                 float* __restrict__ outF,
                                                 ushortT* __restrict__ o0,
                                                 ushortT* __restrict__ o1,
                                                 ushortT* __restrict__ o2) {
    __shared__ __align__(16) ushortT As[128 * 64];
    __shared__ __align__(16) ushortT Bs[128 * 64];
    const int tid = threadIdx.x;
    const int lane = tid & 63, wid = tid >> 6;
    const int wr = wid >> 1, wc = wid & 1;
    const int row0 = blockIdx.y * 128, col0 = blockIdx.x * 128;
    const int r8 = lane >> 3, sp = lane & 7;
    const int srcoff = (sp ^ r8) << 3;  // inverse swizzle on the global side
    f32x4 acc[4][4] = {};

    for (int kc = 0; kc < DIM; kc += 64) {
        __syncthreads();
#pragma unroll
        for (int it = 0; it < 4; it++) {
            int seg = it * 4 + wid;  // 16 segments x 8 rows
            int row = seg * 8 + r8;
            gld16(&A[(size_t)(row0 + row) * DIM + kc + srcoff], &As[seg * 512]);
            gld16(&Bt[(size_t)(col0 + row) * DIM + kc + srcoff], &Bs[seg * 512]);
        }
        __syncthreads();  // drains vmcnt -> tiles ready
#pragma unroll
        for (int ks = 0; ks < 2; ks++) {
            short8 af[4], bfr[4];
#pragma unroll
            for (int m = 0; m < 4; m++) {
                int row = wr * 64 + m * 16 + (lane & 15);
                af[m] = *(const short8*)&As[row * 64 + (((ks * 4 + (lane >> 4)) ^ (row & 7)) << 3)];
            }
#pragma unroll
            for (int n = 0; n < 4; n++) {
                int row = wc * 64 + n * 16 + (lane & 15);
                bfr[n] = *(const short8*)&Bs[row * 64 + (((ks * 4 + (lane >> 4)) ^ (row & 7)) << 3)];
            }
#pragma unroll
            for (int m = 0; m < 4; m++)
#pragma unroll
                for (int n = 0; n < 4; n++)
                    acc[m][n] = __builtin_amdgcn_mfma_f32_16x16x32_bf16(af[m], bfr[n], acc[m][n], 0, 0, 0);
        }
    }

    if (MODE == 0) {
#pragma unroll
        for (int n = 0; n < 4; n++) {
            int c = col0 + wc * 64 + n * 16 + (lane & 15);
            float bv = b0[c];
#pragma unroll
            for (int m = 0; m < 4; m++)
#pragma unroll
                for (int r = 0; r < 4; r++) {
                    int rg = row0 + wr * 64 + m * 16 + (lane >> 4) * 4 + r;
                    outF[(size_t)rg * DIM + c] = acc[m][n][r] + bv;
                }
        }
    } else {
        const int which = col0 >> 10;  // 0=Q 1=K 2=V (tile never straddles)
        const float* bias = which == 0 ? b0 : which == 1 ? b1 : b2;
        ushortT* op = which == 0 ? o0 : which == 1 ? o1 : o2;
        float bb[4];
#pragma unroll
        for (int n = 0; n < 4; n++)
            bb[n] = bias[(col0 + wc * 64 + n * 16 + (lane & 15)) & 1023];
#pragma unroll
        for (int m = 0; m < 4; m++)
#pragma unroll
            for (int n = 0; n < 4; n++)
#pragma unroll
                for (int r = 0; r < 4; r++) acc[m][n][r] += bb[n];
        if (which < 2) {  // fused L2 norm over the 64-wide head row
            float asc = (which == 0) ? ascale[0] : 1.0f;
#pragma unroll
            for (int m = 0; m < 4; m++)
#pragma unroll
                for (int r = 0; r < 4; r++) {
                    float ss = acc[m][0][r] * acc[m][0][r] + acc[m][1][r] * acc[m][1][r] +
                               acc[m][2][r] * acc[m][2][r] + acc[m][3][r] * acc[m][3][r];
#pragma unroll
                    for (int o = 8; o > 0; o >>= 1) ss += __shfl_xor(ss, o);
                    float sc = asc / fmaxf(sqrtf(ss), 1e-12f);
#pragma unroll
                    for (int n = 0; n < 4; n++) acc[m][n][r] *= sc;
                }
        }
#pragma unroll
        for (int n = 0; n < 4; n++) {
            int c = col0 + wc * 64 + n * 16 + (lane & 15);
            int h = (c & 1023) >> 6, d = c & 63;
#pragma unroll
            for (int m = 0; m < 4; m++)
#pragma unroll
                for (int r = 0; r < 4; r++) {
                    int rg = row0 + wr * 64 + m * 16 + (lane >> 4) * 4 + r;
                    int b = rg >> 11, t = rg & (SLEN - 1);
                    op[((size_t)(b * NH + h) * SLEN + t) * DPH + d] = f2bf(acc[m][n][r]);
                }
        }
    }
}

// ---------------------------------------------------------------------------
// V[bh][t][64] bf16 -> Vt[bh][64][2048] bf16 (64x64 tiles via LDS)
// ---------------------------------------------------------------------------
__global__ __launch_bounds__(256) void vtrans(const ushortT* __restrict__ Vh,
                                              ushortT* __restrict__ Vt) {
    __shared__ ushortT tile[64][66];
    const int tid = threadIdx.x;
    const int bh = blockIdx.x, kb = blockIdx.y;
    const size_t base = (size_t)bh * SLEN * DPH;
#pragma unroll
    for (int it = 0; it < 2; it++) {
        int chunk = it * 256 + tid;
        int t = chunk >> 3, c8 = (chunk & 7) * 8;
        short8 v = *(const short8*)&Vh[base + (size_t)(kb * 64 + t) * DPH + c8];
#pragma unroll
        for (int j = 0; j < 8; j++) tile[t][c8 + j] = (ushortT)v[j];
    }
    __syncthreads();
#pragma unroll
    for (int it = 0; it < 2; it++) {
        int chunk = it * 256 + tid;
        int d = chunk >> 3, t8 = (chunk & 7) * 8;
        short8 o;
#pragma unroll
        for (int j = 0; j < 8; j++) o[j] = (short)tile[t8 + j][d];
        *(short8*)&Vt[base + (size_t)d * SLEN + kb * 64 + t8] = o;
    }
}

// ---------------------------------------------------------------------------
// Causal flash attention, bf16 MFMA 16x16x32, exact fixed-shift softmax.
// |score| <= |ascale| (cosine attention), so exp(s - |ascale|) never
// overflows: no running max, no rescale; l reduced once at the end.
// K/V double-buffered in LDS via async global_load_lds issued before the
// compute phase; ONE barrier per key tile. 48 KiB LDS -> 3 blocks/CU.
// Grid: flat 1024; qt = 31-(bid&31) so expensive tiles dispatch first.
// ---------------------------------------------------------------------------
__global__ __launch_bounds__(256) void attn(const ushortT* __restrict__ Q,
                                            const ushortT* __restrict__ K,
                                            const ushortT* __restrict__ Vt,
                                            const float* __restrict__ scale,
                                            ushortT* __restrict__ ctx) {
    __shared__ __align__(16) ushortT Qs[64 * 64];
    __shared__ __align__(16) ushortT Ks[2][64 * 64];
    __shared__ __align__(16) ushortT Vs[2][64 * 64];
    __shared__ __align__(16) ushortT Ps[4 * 16 * 64];
    const int tid = threadIdx.x, lane = tid & 63, wid = tid >> 6;
    const int bid = blockIdx.x;
    const int qt = 31 - (bid & 31), bh = bid >> 5;
    const size_t hb = (size_t)bh * SLEN * DPH;
    const int r8 = lane >> 3, sp = lane & 7;
    const int srcoff = (sp ^ r8) << 3;
    const float mshift = fabsf(scale[0]);

    // prologue: stage Q + K/V tile 0
#pragma unroll
    for (int it = 0; it < 2; it++) {
        int seg = it * 4 + wid;
        int row = seg * 8 + r8;
        gld16(&Q[hb + (size_t)(qt * 64 + row) * DPH + srcoff], &Qs[seg * 512]);
        gld16(&K[hb + (size_t)row * DPH + srcoff], &Ks[0][seg * 512]);
        gld16(&Vt[hb + (size_t)row * SLEN + srcoff], &Vs[0][seg * 512]);
    }
    __syncthreads();

    short8 aq[2];
    {
        int row = wid * 16 + (lane & 15);
#pragma unroll
        for (int ks = 0; ks < 2; ks++)
            aq[ks] = *(const short8*)&Qs[row * 64 + (((ks * 4 + (lane >> 4)) ^ (row & 7)) << 3)];
    }

    f32x4 accd[4] = {};
    float lpart[4] = {0.f, 0.f, 0.f, 0.f};

    for (int kb = 0; kb <= qt; kb++) {
        const int cur = kb & 1;
        if (kb < qt) {  // async prefetch next tile into the other buffer
            const int nxt = cur ^ 1;
#pragma unroll
            for (int it = 0; it < 2; it++) {
                int seg = it * 4 + wid;
                int row = seg * 8 + r8;
                gld16(&K[hb + (size_t)((kb + 1) * 64 + row) * DPH + srcoff], &Ks[nxt][seg * 512]);
                gld16(&Vt[hb + (size_t)row * SLEN + (kb + 1) * 64 + srcoff], &Vs[nxt][seg * 512]);
            }
        }

        // S = Q K^T
        f32x4 sf[4] = {};
#pragma unroll
        for (int ks = 0; ks < 2; ks++)
#pragma unroll
            for (int j = 0; j < 4; j++) {
                int row = j * 16 + (lane & 15);
                short8 bk = *(const short8*)&Ks[cur][row * 64 + (((ks * 4 + (lane >> 4)) ^ (row & 7)) << 3)];
                sf[j] = __builtin_amdgcn_mfma_f32_16x16x32_bf16(aq[ks], bk, sf[j], 0, 0, 0);
            }

        if (kb == qt) {  // diagonal: causal mask
#pragma unroll
            for (int j = 0; j < 4; j++)
#pragma unroll
                for (int r = 0; r < 4; r++) {
                    int keyl = j * 16 + (lane & 15);
                    int ql = wid * 16 + (lane >> 4) * 4 + r;
                    if (keyl > ql) sf[j][r] = -INFINITY;
                }
        }

        // fixed-shift softmax numerator; deferred denominator
#pragma unroll
        for (int r = 0; r < 4; r++) {
            int prow = (lane >> 4) * 4 + r;
#pragma unroll
            for (int j = 0; j < 4; j++) {
                float p = __expf(sf[j][r] - mshift);
                lpart[r] += p;
                int col = j * 16 + (lane & 15);
                Ps[(wid * 16 + prow) * 64 + (((col >> 3) ^ (prow & 7)) << 3) + (col & 7)] = f2bf(p);
            }
        }

        // PV
#pragma unroll
        for (int ks = 0; ks < 2; ks++) {
            int prow = lane & 15;
            short8 ap = *(const short8*)&Ps[(wid * 16 + prow) * 64 +
                                            (((ks * 4 + (lane >> 4)) ^ (prow & 7)) << 3)];
#pragma unroll
            for (int jd = 0; jd < 4; jd++) {
                int drow = jd * 16 + (lane & 15);
                short8 bv = *(const short8*)&Vs[cur][drow * 64 +
                                                     (((ks * 4 + (lane >> 4)) ^ (drow & 7)) << 3)];
                accd[jd] = __builtin_amdgcn_mfma_f32_16x16x32_bf16(ap, bv, accd[jd], 0, 0, 0);
            }
        }
        __syncthreads();  // drains prefetch vmcnt; orders buffer reuse
    }

#pragma unroll
    for (int r = 0; r < 4; r++)
#pragma unroll
        for (int o = 8; o > 0; o >>= 1) lpart[r] += __shfl_xor(lpart[r], o);

    const int b = bh >> 4, h = bh & 15;
#pragma unroll
    for (int jd = 0; jd < 4; jd++)
#pragma unroll
        for (int r = 0; r < 4; r++) {
            int ql = wid * 16 + (lane >> 4) * 4 + r;
            int t = qt * 64 + ql;
            int d = jd * 16 + (lane & 15);
            ctx[(size_t)(b * SLEN + t) * DIM + h * 64 + d] = f2bf(accd[jd][r] / lpart[r]);
        }
}

// ---------------------------------------------------------------------------
// inputs: 0 x, 1 mask(unused), 2 Wq, 3 bq, 4 Wk, 5 bk, 6 Wv, 7 bv, 8 Wo,
// 9 bo, 10 attention_scale
// ---------------------------------------------------------------------------
extern "C" void kernel_launch(void* const* d_in, const int* in_sizes, int n_in,
                              void* d_out, int out_size, void* d_ws,
                              size_t ws_size, hipStream_t stream) {
    const float* x = (const float*)d_in[0];
    const float* Wq = (const float*)d_in[2];
    const float* bq = (const float*)d_in[3];
    const float* Wk = (const float*)d_in[4];
    const float* bk = (const float*)d_in[5];
    const float* Wv = (const float*)d_in[6];
    const float* bv = (const float*)d_in[7];
    const float* Wo = (const float*)d_in[8];
    const float* bo = (const float*)d_in[9];
    const float* ascale = (const float*)d_in[10];
    float* outF = (float*)d_out;

    unsigned char* ws = (unsigned char*)d_ws;
    const size_t MB = 1u << 20;
    ushortT* xb = (ushortT*)(ws);               // 8 MB; dead after QKV GEMM
    ushortT* VtB = (ushortT*)(ws);              // aliases xb
    ushortT* Wqkvt = (ushortT*)(ws + 8 * MB);   // [3072][1024] bf16, 6 MB
    ushortT* Wot = (ushortT*)(ws + 14 * MB);    // 2 MB
    ushortT* Qb = (ushortT*)(ws + 16 * MB);     // 8 MB each
    ushortT* Kb = (ushortT*)(ws + 24 * MB);
    ushortT* Vb = (ushortT*)(ws + 32 * MB);
    ushortT* ctxb = (ushortT*)(ws + 40 * MB);   // total 48 MB

    cvt_x<<<NTOK * DIM / (8 * 256), 256, 0, stream>>>(x, xb);
    cvt_wt<<<dim3(16, 16, 4), 256, 0, stream>>>(Wq, Wk, Wv, Wo, Wqkvt,
                                                Wqkvt + (size_t)1024 * 1024,
                                                Wqkvt + (size_t)2048 * 1024, Wot);

    // fused QKV projection + bias + (Q,K) L2-norm + bf16 head-major write
    gemm_bf16<1><<<dim3(3 * DIM / 128, NTOK / 128), 256, 0, stream>>>(
        xb, Wqkvt, bq, bk, bv, ascale, nullptr, Qb, Kb, Vb);

    vtrans<<<dim3(32, 32), 256, 0, stream>>>(Vb, VtB);

    attn<<<dim3(32 * 32), 256, 0, stream>>>(Qb, Kb, VtB, ascale, ctxb);

    gemm_bf16<0><<<dim3(DIM / 128, NTOK / 128), 256, 0, stream>>>(
        ctxb, Wot, bo, nullptr, nullptr, nullptr, outF, nullptr, nullptr, nullptr);
}

// Round 5
// 122.911 us; speedup vs baseline: 13.2545x; 1.3964x over previous
//
#include <hip/hip_runtime.h>
#include <math.h>

#define NH 16
#define DPH 64
#define SLEN 2048
#define BSZ 2
#define DIM 1024
#define NTOK (BSZ * SLEN)
#define LOG2E 1.44269504088896f

typedef unsigned short ushortT;
typedef __attribute__((ext_vector_type(8))) short short8;
typedef __attribute__((ext_vector_type(4))) short s16x4;
typedef __attribute__((ext_vector_type(4))) float f32x4;

typedef __attribute__((address_space(1))) const unsigned int gu32c;
typedef __attribute__((address_space(3))) unsigned int lu32;

__device__ __forceinline__ void gld16(const void* g, void* l) {
    __builtin_amdgcn_global_load_lds((gu32c*)g, (lu32*)l, 16, 0, 0);
}

__device__ __forceinline__ ushortT f2bf(float f) {
    unsigned int u = __builtin_bit_cast(unsigned int, f);
    u = u + 0x7fffu + ((u >> 16) & 1u);  // RNE
    return (ushortT)(u >> 16);
}

// ---------------------------------------------------------------------------
// x (fp32) -> bf16, 8 elems/thread
// ---------------------------------------------------------------------------
__global__ __launch_bounds__(256) void cvt_x(const float* __restrict__ x,
                                             ushortT* __restrict__ xb) {
    size_t i = (size_t)blockIdx.x * 256 + threadIdx.x;
    float4 a = *(const float4*)&x[i * 8];
    float4 b = *(const float4*)&x[i * 8 + 4];
    short8 v;
    v[0] = (short)f2bf(a.x); v[1] = (short)f2bf(a.y);
    v[2] = (short)f2bf(a.z); v[3] = (short)f2bf(a.w);
    v[4] = (short)f2bf(b.x); v[5] = (short)f2bf(b.y);
    v[6] = (short)f2bf(b.z); v[7] = (short)f2bf(b.w);
    *(short8*)&xb[i * 8] = v;
}

// ---------------------------------------------------------------------------
// W[k][n] fp32 -> Wt[n][k] bf16 (transpose + convert), 64x64 tiles
// ---------------------------------------------------------------------------
__global__ __launch_bounds__(256) void cvt_wt(const float* __restrict__ W0, const float* __restrict__ W1,
                                              const float* __restrict__ W2, const float* __restrict__ W3,
                                              ushortT* __restrict__ T0, ushortT* __restrict__ T1,
                                              ushortT* __restrict__ T2, ushortT* __restrict__ T3) {
    const float* W = blockIdx.z == 0 ? W0 : blockIdx.z == 1 ? W1 : blockIdx.z == 2 ? W2 : W3;
    ushortT* T = blockIdx.z == 0 ? T0 : blockIdx.z == 1 ? T1 : blockIdx.z == 2 ? T2 : T3;
    __shared__ float tile[64][65];
    const int tid = threadIdx.x;
    const int kb = blockIdx.y * 64, nb = blockIdx.x * 64;
#pragma unroll
    for (int it = 0; it < 4; it++) {
        int chunk = it * 256 + tid;
        int r = chunk >> 4, c4 = (chunk & 15) * 4;
        *(float4*)&tile[r][c4] = *(const float4*)&W[(size_t)(kb + r) * DIM + nb + c4];
    }
    __syncthreads();
#pragma unroll
    for (int it = 0; it < 2; it++) {
        int chunk = it * 256 + tid;
        int n = chunk >> 3, k8 = (chunk & 7) * 8;
        short8 o;
#pragma unroll
        for (int j = 0; j < 8; j++) o[j] = (short)f2bf(tile[k8 + j][n]);
        *(short8*)&T[(size_t)(nb + n) * DIM + kb + k8] = o;
    }
}

// ---------------------------------------------------------------------------
// bf16 MFMA GEMM, 128x128 tile, BK=64, global_load_lds staging.
// MODE 0: fp32 [M][1024] + b0 -> outF            (O-projection)
// MODE 1: fused QKV (N=3072): Q/K L2-normalized in epilogue; Q additionally
//         scaled by ascale*log2(e) (attn uses exp2); bf16 head-major out.
// ---------------------------------------------------------------------------
template <int MODE>
__global__ __launch_bounds__(256) void gemm_bf16(const ushortT* __restrict__ A,
                                                 const ushortT* __restrict__ Bt,
                                                 const float* __restrict__ b0,
                                                 const float* __restrict__ b1,
                                                 const float* __restrict__ b2,
                                                 const float* __restrict__ ascale,
                                                 float* __restrict__ outF,
                                                 ushortT* __restrict__ o0,
                                                 ushortT* __restrict__ o1,
                                                 ushortT* __restrict__ o2) {
    __shared__ __align__(16) ushortT As[128 * 64];
    __shared__ __align__(16) ushortT Bs[128 * 64];
    const int tid = threadIdx.x;
    const int lane = tid & 63, wid = tid >> 6;
    const int wr = wid >> 1, wc = wid & 1;
    const int row0 = blockIdx.y * 128, col0 = blockIdx.x * 128;
    const int r8 = lane >> 3, sp = lane & 7;
    const int srcoff = (sp ^ r8) << 3;  // inverse swizzle on the global side
    f32x4 acc[4][4] = {};

    for (int kc = 0; kc < DIM; kc += 64) {
        __syncthreads();
#pragma unroll
        for (int it = 0; it < 4; it++) {
            int seg = it * 4 + wid;  // 16 segments x 8 rows
            int row = seg * 8 + r8;
            gld16(&A[(size_t)(row0 + row) * DIM + kc + srcoff], &As[seg * 512]);
            gld16(&Bt[(size_t)(col0 + row) * DIM + kc + srcoff], &Bs[seg * 512]);
        }
        __syncthreads();  // drains vmcnt -> tiles ready
#pragma unroll
        for (int ks = 0; ks < 2; ks++) {
            short8 af[4], bfr[4];
#pragma unroll
            for (int m = 0; m < 4; m++) {
                int row = wr * 64 + m * 16 + (lane & 15);
                af[m] = *(const short8*)&As[row * 64 + (((ks * 4 + (lane >> 4)) ^ (row & 7)) << 3)];
            }
#pragma unroll
            for (int n = 0; n < 4; n++) {
                int row = wc * 64 + n * 16 + (lane & 15);
                bfr[n] = *(const short8*)&Bs[row * 64 + (((ks * 4 + (lane >> 4)) ^ (row & 7)) << 3)];
            }
#pragma unroll
            for (int m = 0; m < 4; m++)
#pragma unroll
                for (int n = 0; n < 4; n++)
                    acc[m][n] = __builtin_amdgcn_mfma_f32_16x16x32_bf16(af[m], bfr[n], acc[m][n], 0, 0, 0);
        }
    }

    if (MODE == 0) {
#pragma unroll
        for (int n = 0; n < 4; n++) {
            int c = col0 + wc * 64 + n * 16 + (lane & 15);
            float bv = b0[c];
#pragma unroll
            for (int m = 0; m < 4; m++)
#pragma unroll
                for (int r = 0; r < 4; r++) {
                    int rg = row0 + wr * 64 + m * 16 + (lane >> 4) * 4 + r;
                    outF[(size_t)rg * DIM + c] = acc[m][n][r] + bv;
                }
        }
    } else {
        const int which = col0 >> 10;  // 0=Q 1=K 2=V
        const float* bias = which == 0 ? b0 : which == 1 ? b1 : b2;
        ushortT* op = which == 0 ? o0 : which == 1 ? o1 : o2;
        float bb[4];
#pragma unroll
        for (int n = 0; n < 4; n++)
            bb[n] = bias[(col0 + wc * 64 + n * 16 + (lane & 15)) & 1023];
#pragma unroll
        for (int m = 0; m < 4; m++)
#pragma unroll
            for (int n = 0; n < 4; n++)
#pragma unroll
                for (int r = 0; r < 4; r++) acc[m][n][r] += bb[n];
        if (which < 2) {  // fused L2 norm over the 64-wide head row
            float asc = (which == 0) ? ascale[0] * LOG2E : 1.0f;
#pragma unroll
            for (int m = 0; m < 4; m++)
#pragma unroll
                for (int r = 0; r < 4; r++) {
                    float ss = acc[m][0][r] * acc[m][0][r] + acc[m][1][r] * acc[m][1][r] +
                               acc[m][2][r] * acc[m][2][r] + acc[m][3][r] * acc[m][3][r];
#pragma unroll
                    for (int o = 8; o > 0; o >>= 1) ss += __shfl_xor(ss, o);
                    float sc = asc / fmaxf(sqrtf(ss), 1e-12f);
#pragma unroll
                    for (int n = 0; n < 4; n++) acc[m][n][r] *= sc;
                }
        }
#pragma unroll
        for (int n = 0; n < 4; n++) {
            int c = col0 + wc * 64 + n * 16 + (lane & 15);
            int h = (c & 1023) >> 6, d = c & 63;
#pragma unroll
            for (int m = 0; m < 4; m++)
#pragma unroll
                for (int r = 0; r < 4; r++) {
                    int rg = row0 + wr * 64 + m * 16 + (lane >> 4) * 4 + r;
                    int b = rg >> 11, t = rg & (SLEN - 1);
                    op[((size_t)(b * NH + h) * SLEN + t) * DPH + d] = f2bf(acc[m][n][r]);
                }
        }
    }
}

// ---------------------------------------------------------------------------
// V[bh][t][64] -> VF[bh][kt][c][lane][8] in MFMA B-frag order:
// chunk c=(jd*2+ks); VF[..][c][l][e] = V[kt*64 + ks*32+8*(l>>4)+e][jd*16+(l&15)]
// so attn's V-frag load is a fully-coalesced 1KB global read per chunk.
// ---------------------------------------------------------------------------
__global__ __launch_bounds__(256) void vfprep(const ushortT* __restrict__ Vh,
                                              ushortT* __restrict__ VF) {
    __shared__ ushortT tile[64][65];
    const int tid = threadIdx.x;
    const int bh = blockIdx.x, kt = blockIdx.y;
    const size_t base = (size_t)bh * SLEN * DPH;
#pragma unroll
    for (int it = 0; it < 2; it++) {
        int chunk = it * 256 + tid;
        int t = chunk >> 3, c8 = (chunk & 7) * 8;
        short8 v = *(const short8*)&Vh[base + (size_t)(kt * 64 + t) * DPH + c8];
#pragma unroll
        for (int j = 0; j < 8; j++) tile[t][c8 + j] = (ushortT)v[j];
    }
    __syncthreads();
#pragma unroll
    for (int it = 0; it < 2; it++) {
        int o = it * 256 + tid;            // 0..511
        int c = o >> 6, l = o & 63;
        int jd = c >> 1, ks = c & 1;
        int d = jd * 16 + (l & 15);
        int t0 = ks * 32 + 8 * (l >> 4);
        short8 v;
#pragma unroll
        for (int e = 0; e < 8; e++) v[e] = (short)tile[t0 + e][d];
        *(short8*)&VF[(((size_t)bh * 32 + kt) * 512 + o) * 8] = v;
    }
}

// ---------------------------------------------------------------------------
// Causal flash attention, swapped-QK^T, exact fixed-shift exp2 softmax.
// 512 thr = 8 waves: waves 0-3 -> q-tile 31-p, waves 4-7 -> q-tile p
// (paired: every block does exactly 33 active wave-tile-quads).
// K: reg-staged -> LDS (swizzled); V: direct global frag loads from VF (L2);
// Q: direct global frag loads; P: wave-private LDS, b64 writes / b128 reads.
// LDS = 8KB K + 16KB P = 24KB.
// ---------------------------------------------------------------------------
__global__ __launch_bounds__(512, 4) void attn(const ushortT* __restrict__ Q,
                                               const ushortT* __restrict__ K,
                                               const ushortT* __restrict__ VF,
                                               const float* __restrict__ scale,
                                               ushortT* __restrict__ ctx) {
    __shared__ __align__(16) ushortT Ks[64 * 64];
    __shared__ __align__(16) ushortT Ps[8 * 16 * 64];
    const int tid = threadIdx.x, lane = tid & 63, wid = tid >> 6;
    const int wg = wid & 3, sg = wid >> 2;
    const int bh = blockIdx.x, p = blockIdx.y;
    const int qt = sg ? p : 31 - p;
    const int kbmax = 31 - p;
    const size_t hb = (size_t)bh * SLEN * DPH;
    const int lo = lane & 15, hi = lane >> 4;
    const float mshift = fabsf(scale[0]) * LOG2E;

    // Q frags straight from global (once per block)
    short8 aq[2];
    {
        const int qrow = qt * 64 + wg * 16 + lo;
#pragma unroll
        for (int ks = 0; ks < 2; ks++)
            aq[ks] = *(const short8*)&Q[hb + (size_t)qrow * DPH + ks * 32 + 8 * hi];
    }

    // K staging: thread owns chunk tid (row=tid>>3, slot=tid&7)
    const int srow = tid >> 3, sslot = tid & 7;
    const int sldsoff = srow * 64 + ((sslot ^ (srow & 7)) << 3);
    uint4 kr = *(const uint4*)&K[hb + (size_t)srow * DPH + sslot * 8];
    *(uint4*)&Ks[sldsoff] = kr;
    __syncthreads();

    f32x4 accd[4] = {};
    float lp = 0.f;

    for (int kb = 0; kb <= kbmax; kb++) {
        if (kb < kbmax)  // issue next K tile early (latency hides under compute)
            kr = *(const uint4*)&K[hb + (size_t)((kb + 1) * 64 + srow) * DPH + sslot * 8];

        if (kb <= qt) {  // wave-uniform activity predicate
            // V frags for this tile: 8 coalesced 1KB loads, L2-served
            short8 bv[8];
            const ushortT* vt = &VF[(((size_t)bh * 32 + kb) * 512 + lane) * 8];
#pragma unroll
            for (int c = 0; c < 8; c++) bv[c] = *(const short8*)&vt[(size_t)c * 512];

            // S^T = mfma(K, Q): lane lo = q, C rows = keys
            f32x4 sf[4] = {};
#pragma unroll
            for (int ks = 0; ks < 2; ks++)
#pragma unroll
                for (int j = 0; j < 4; j++) {
                    int row = j * 16 + lo;
                    short8 bk = *(const short8*)&Ks[row * 64 + (((ks * 4 + hi) ^ (row & 7)) << 3)];
                    sf[j] = __builtin_amdgcn_mfma_f32_16x16x32_bf16(bk, aq[ks], sf[j], 0, 0, 0);
                }

            if (kb == qt) {  // diagonal: mask key > q
#pragma unroll
                for (int j = 0; j < 4; j++)
#pragma unroll
                    for (int r = 0; r < 4; r++)
                        if (j * 16 + 4 * hi + r > wg * 16 + lo) sf[j][r] = -INFINITY;
            }

            // exp2 softmax numerator; P write: one b64 per j (k-consecutive!)
#pragma unroll
            for (int j = 0; j < 4; j++) {
                s16x4 pk;
#pragma unroll
                for (int r = 0; r < 4; r++) {
                    float pv = __builtin_amdgcn_exp2f(sf[j][r] - mshift);
                    lp += pv;
                    pk[r] = (short)f2bf(pv);
                }
                int slot = (4 * j + hi) ^ (2 * (lo & 7));
                *(s16x4*)&Ps[wid * 1024 + lo * 64 + slot * 4] = pk;
            }

            // PV: A=P (wave-private LDS), B=V frags (regs)
#pragma unroll
            for (int ks = 0; ks < 2; ks++) {
                int slot0 = (8 * ks + 2 * hi) ^ (2 * (lo & 7));
                short8 ap = *(const short8*)&Ps[wid * 1024 + lo * 64 + slot0 * 4];
#pragma unroll
                for (int jd = 0; jd < 4; jd++)
                    accd[jd] = __builtin_amdgcn_mfma_f32_16x16x32_bf16(ap, bv[jd * 2 + ks], accd[jd], 0, 0, 0);
            }
        }

        __syncthreads();  // all waves done reading Ks
        if (kb < kbmax) {
            *(uint4*)&Ks[sldsoff] = kr;  // compiler waits vmcnt on kr
            __syncthreads();
        }
    }

    // row-sum: lane holds partial for q=lo; reduce over hi groups,
    // then redistribute to C-row lanes (row = 4*hi+r lives at lane lo=4*hi+r)
    lp += __shfl_xor(lp, 16);
    lp += __shfl_xor(lp, 32);

    const int b = bh >> 4, h = bh & 15;
#pragma unroll
    for (int r = 0; r < 4; r++) {
        float lr = __shfl(lp, (lane & 48) | (4 * hi + r));
        float inv = 1.0f / lr;
        int t = qt * 64 + wg * 16 + 4 * hi + r;
#pragma unroll
        for (int jd = 0; jd < 4; jd++) {
            int d = jd * 16 + lo;
            ctx[(size_t)(b * SLEN + t) * DIM + h * 64 + d] = f2bf(accd[jd][r] * inv);
        }
    }
}

// ---------------------------------------------------------------------------
// inputs: 0 x, 1 mask(unused), 2 Wq, 3 bq, 4 Wk, 5 bk, 6 Wv, 7 bv, 8 Wo,
// 9 bo, 10 attention_scale
// ---------------------------------------------------------------------------
extern "C" void kernel_launch(void* const* d_in, const int* in_sizes, int n_in,
                              void* d_out, int out_size, void* d_ws,
                              size_t ws_size, hipStream_t stream) {
    const float* x = (const float*)d_in[0];
    const float* Wq = (const float*)d_in[2];
    const float* bq = (const float*)d_in[3];
    const float* Wk = (const float*)d_in[4];
    const float* bk = (const float*)d_in[5];
    const float* Wv = (const float*)d_in[6];
    const float* bv = (const float*)d_in[7];
    const float* Wo = (const float*)d_in[8];
    const float* bo = (const float*)d_in[9];
    const float* ascale = (const float*)d_in[10];
    float* outF = (float*)d_out;

    unsigned char* ws = (unsigned char*)d_ws;
    const size_t MB = 1u << 20;
    ushortT* xb = (ushortT*)(ws);               // 8 MB; dead after QKV GEMM
    ushortT* VFb = (ushortT*)(ws);              // aliases xb (written after)
    ushortT* Wqkvt = (ushortT*)(ws + 8 * MB);   // 6 MB
    ushortT* Wot = (ushortT*)(ws + 14 * MB);    // 2 MB
    ushortT* Qb = (ushortT*)(ws + 16 * MB);     // 8 MB
    ushortT* Kb = (ushortT*)(ws + 24 * MB);     // 8 MB
    ushortT* Vb = (ushortT*)(ws + 32 * MB);     // 8 MB; dead after vfprep
    ushortT* ctxb = Vb;                         // aliases Vb; total 40 MB

    cvt_x<<<NTOK * DIM / (8 * 256), 256, 0, stream>>>(x, xb);
    cvt_wt<<<dim3(16, 16, 4), 256, 0, stream>>>(Wq, Wk, Wv, Wo, Wqkvt,
                                                Wqkvt + (size_t)1024 * 1024,
                                                Wqkvt + (size_t)2048 * 1024, Wot);

    gemm_bf16<1><<<dim3(3 * DIM / 128, NTOK / 128), 256, 0, stream>>>(
        xb, Wqkvt, bq, bk, bv, ascale, nullptr, Qb, Kb, Vb);

    vfprep<<<dim3(32, 32), 256, 0, stream>>>(Vb, VFb);

    attn<<<dim3(32, 16), 512, 0, stream>>>(Qb, Kb, VFb, ascale, ctxb);

    gemm_bf16<0><<<dim3(DIM / 128, NTOK / 128), 256, 0, stream>>>(
        ctxb, Wot, bo, nullptr, nullptr, nullptr, outF, nullptr, nullptr, nullptr);
}

// Round 6
// 111.805 us; speedup vs baseline: 14.5712x; 1.0993x over previous
//
#include <hip/hip_runtime.h>
#include <math.h>

#define NH 16
#define DPH 64
#define SLEN 2048
#define BSZ 2
#define DIM 1024
#define NTOK (BSZ * SLEN)
#define LOG2E 1.44269504088896f

typedef unsigned short ushortT;
typedef __attribute__((ext_vector_type(8))) short short8;
typedef __attribute__((ext_vector_type(4))) short s16x4;
typedef __attribute__((ext_vector_type(4))) float f32x4;

typedef __attribute__((address_space(1))) const unsigned int gu32c;
typedef __attribute__((address_space(3))) unsigned int lu32;

__device__ __forceinline__ void gld16(const void* g, void* l) {
    __builtin_amdgcn_global_load_lds((gu32c*)g, (lu32*)l, 16, 0, 0);
}

__device__ __forceinline__ ushortT f2bf(float f) {
    unsigned int u = __builtin_bit_cast(unsigned int, f);
    u = u + 0x7fffu + ((u >> 16) & 1u);  // RNE
    return (ushortT)(u >> 16);
}

// ---------------------------------------------------------------------------
// x (fp32) -> bf16, 8 elems/thread
// ---------------------------------------------------------------------------
__global__ __launch_bounds__(256) void cvt_x(const float* __restrict__ x,
                                             ushortT* __restrict__ xb) {
    size_t i = (size_t)blockIdx.x * 256 + threadIdx.x;
    float4 a = *(const float4*)&x[i * 8];
    float4 b = *(const float4*)&x[i * 8 + 4];
    short8 v;
    v[0] = (short)f2bf(a.x); v[1] = (short)f2bf(a.y);
    v[2] = (short)f2bf(a.z); v[3] = (short)f2bf(a.w);
    v[4] = (short)f2bf(b.x); v[5] = (short)f2bf(b.y);
    v[6] = (short)f2bf(b.z); v[7] = (short)f2bf(b.w);
    *(short8*)&xb[i * 8] = v;
}

// ---------------------------------------------------------------------------
// W[k][n] fp32 -> Wt[n][k] bf16 (transpose + convert), 64x64 tiles
// ---------------------------------------------------------------------------
__global__ __launch_bounds__(256) void cvt_wt(const float* __restrict__ W0, const float* __restrict__ W1,
                                              const float* __restrict__ W2, const float* __restrict__ W3,
                                              ushortT* __restrict__ T0, ushortT* __restrict__ T1,
                                              ushortT* __restrict__ T2, ushortT* __restrict__ T3) {
    const float* W = blockIdx.z == 0 ? W0 : blockIdx.z == 1 ? W1 : blockIdx.z == 2 ? W2 : W3;
    ushortT* T = blockIdx.z == 0 ? T0 : blockIdx.z == 1 ? T1 : blockIdx.z == 2 ? T2 : T3;
    __shared__ float tile[64][65];
    const int tid = threadIdx.x;
    const int kb = blockIdx.y * 64, nb = blockIdx.x * 64;
#pragma unroll
    for (int it = 0; it < 4; it++) {
        int chunk = it * 256 + tid;
        int r = chunk >> 4, c4 = (chunk & 15) * 4;
        *(float4*)&tile[r][c4] = *(const float4*)&W[(size_t)(kb + r) * DIM + nb + c4];
    }
    __syncthreads();
#pragma unroll
    for (int it = 0; it < 2; it++) {
        int chunk = it * 256 + tid;
        int n = chunk >> 3, k8 = (chunk & 7) * 8;
        short8 o;
#pragma unroll
        for (int j = 0; j < 8; j++) o[j] = (short)f2bf(tile[k8 + j][n]);
        *(short8*)&T[(size_t)(nb + n) * DIM + kb + k8] = o;
    }
}

// ---------------------------------------------------------------------------
// Fused QKV GEMM: C = xb(4096,1024) @ Wqkv^T(3072,1024) + bias, 128x128 tile,
// BK=64, global_load_lds staging. Epilogue per wave (64 tokens x 1 head):
// Q/K: L2 norm (+ascale*log2e on Q), bf16, LDS-bounce -> contiguous 8KB
// head-major store. V: LDS-bounce -> VF MFMA-fragment layout directly
// (replaces the old vfprep kernel).
// ---------------------------------------------------------------------------
__global__ __launch_bounds__(256) void gemm_qkv(const ushortT* __restrict__ A,
                                                const ushortT* __restrict__ Bt,
                                                const float* __restrict__ bq,
                                                const float* __restrict__ bk,
                                                const float* __restrict__ bv,
                                                const float* __restrict__ ascale,
                                                ushortT* __restrict__ Qb,
                                                ushortT* __restrict__ Kb,
                                                ushortT* __restrict__ VF) {
    __shared__ __align__(16) ushortT As[128 * 64];
    __shared__ __align__(16) ushortT Bs[128 * 64];
    const int tid = threadIdx.x;
    const int lane = tid & 63, wid = tid >> 6;
    const int wr = wid >> 1, wc = wid & 1;
    const int lo = lane & 15, hi = lane >> 4;
    const int row0 = blockIdx.y * 128, col0 = blockIdx.x * 128;
    const int r8 = lane >> 3, sp = lane & 7;
    const int srcoff = (sp ^ r8) << 3;  // inverse swizzle on the global side
    f32x4 acc[4][4] = {};

    for (int kc = 0; kc < DIM; kc += 64) {
        __syncthreads();
#pragma unroll
        for (int it = 0; it < 4; it++) {
            int seg = it * 4 + wid;  // 16 segments x 8 rows
            int row = seg * 8 + r8;
            gld16(&A[(size_t)(row0 + row) * DIM + kc + srcoff], &As[seg * 512]);
            gld16(&Bt[(size_t)(col0 + row) * DIM + kc + srcoff], &Bs[seg * 512]);
        }
        __syncthreads();  // drains vmcnt -> tiles ready
#pragma unroll
        for (int ks = 0; ks < 2; ks++) {
            short8 af[4], bfr[4];
#pragma unroll
            for (int m = 0; m < 4; m++) {
                int row = wr * 64 + m * 16 + lo;
                af[m] = *(const short8*)&As[row * 64 + (((ks * 4 + hi) ^ (row & 7)) << 3)];
            }
#pragma unroll
            for (int n = 0; n < 4; n++) {
                int row = wc * 64 + n * 16 + lo;
                bfr[n] = *(const short8*)&Bs[row * 64 + (((ks * 4 + hi) ^ (row & 7)) << 3)];
            }
#pragma unroll
            for (int m = 0; m < 4; m++)
#pragma unroll
                for (int n = 0; n < 4; n++)
                    acc[m][n] = __builtin_amdgcn_mfma_f32_16x16x32_bf16(af[m], bfr[n], acc[m][n], 0, 0, 0);
        }
    }

    // ---- epilogue: wave tile = 64 tokens x 64 d (one head) ----
    const int cg = col0 + wc * 64;        // global col of this wave's slab
    const int which = cg >> 10;           // 0=Q 1=K 2=V
    const int cwin = cg & 1023;
    const int h = cwin >> 6;
    const int t0g = row0 + wr * 64;
    const int b = t0g >> 11, tok0 = t0g & (SLEN - 1);
    const float* bias = which == 0 ? bq : which == 1 ? bk : bv;

    float bb[4];
#pragma unroll
    for (int n = 0; n < 4; n++) bb[n] = bias[cwin + n * 16 + lo];
#pragma unroll
    for (int m = 0; m < 4; m++)
#pragma unroll
        for (int n = 0; n < 4; n++)
#pragma unroll
            for (int r = 0; r < 4; r++) acc[m][n][r] += bb[n];

    if (which < 2) {  // fused L2 norm over the 64-wide head row
        float asc = (which == 0) ? ascale[0] * LOG2E : 1.0f;
#pragma unroll
        for (int m = 0; m < 4; m++)
#pragma unroll
            for (int r = 0; r < 4; r++) {
                float ss = acc[m][0][r] * acc[m][0][r] + acc[m][1][r] * acc[m][1][r] +
                           acc[m][2][r] * acc[m][2][r] + acc[m][3][r] * acc[m][3][r];
#pragma unroll
                for (int o = 8; o > 0; o >>= 1) ss += __shfl_xor(ss, o);
                float sc = asc / fmaxf(sqrtf(ss), 1e-12f);
#pragma unroll
                for (int n = 0; n < 4; n++) acc[m][n][r] *= sc;
            }
    }

    __syncthreads();  // all waves done reading As/Bs in the K-loop
    // wave-private 8KB bounce region (swizzle: 16B chunk cc ^ (row>>3))
    ushortT* tl = (wid < 2) ? &As[wid * 4096] : &Bs[(wid - 2) * 4096];
#pragma unroll
    for (int m = 0; m < 4; m++)
#pragma unroll
        for (int n = 0; n < 4; n++)
#pragma unroll
            for (int r = 0; r < 4; r++) {
                int row = m * 16 + hi * 4 + r;
                int col = n * 16 + lo;
                int cc = col >> 3;
                tl[row * 64 + ((cc ^ (row >> 3)) << 3) + (col & 7)] = f2bf(acc[m][n][r]);
            }
    // in-wave DS ordering: write->read same region needs no barrier

    if (which < 2) {
        ushortT* op = which == 0 ? Qb : Kb;
        const size_t base = ((size_t)(b * NH + h) * SLEN + tok0) * DPH;
#pragma unroll
        for (int j = 0; j < 8; j++) {
            int cid = j * 64 + lane;  // 512 16B chunks: row-major [64][8]
            int r2 = cid >> 3, cc = cid & 7;
            uint4 v = *(const uint4*)&tl[r2 * 64 + ((cc ^ (r2 >> 3)) << 3)];
            *(uint4*)&op[base + (size_t)cid * 8] = v;
        }
    } else {
        const int kt = tok0 >> 6;
        const size_t base = ((size_t)(b * NH + h) * 32 + kt) * 4096;
#pragma unroll
        for (int c = 0; c < 8; c++) {
            short8 v;
#pragma unroll
            for (int e = 0; e < 8; e++) {
                int rowL = (c & 1) * 32 + hi * 8 + e;
                int colL = (c >> 1) * 16 + lo;
                int cc2 = colL >> 3;
                v[e] = (short)tl[rowL * 64 + ((cc2 ^ (rowL >> 3)) << 3) + (colL & 7)];
            }
            *(short8*)&VF[base + (size_t)(c * 64 + lane) * 8] = v;
        }
    }
}

// ---------------------------------------------------------------------------
// O-projection: out = ctx(4096,1024) @ Wo^T(1024,1024) + bo, fp32 out.
// 64x128 tile, BK=64 -> grid 8x64 = 512 blocks (2/CU). 4 waves 2x2,
// wave tile 32x64, acc[2][4]. Epilogue LDS-bounced to float4 stores.
// ---------------------------------------------------------------------------
__global__ __launch_bounds__(256) void gemm_oproj(const ushortT* __restrict__ A,
                                                  const ushortT* __restrict__ Bt,
                                                  const float* __restrict__ bias,
                                                  float* __restrict__ outF) {
    __shared__ __align__(16) unsigned char lbuf[32768];
    ushortT* As = (ushortT*)lbuf;             // [64][64] bf16, 8KB
    ushortT* Bs = (ushortT*)(lbuf + 8192);    // [128][64] bf16, 16KB
    const int tid = threadIdx.x;
    const int lane = tid & 63, wid = tid >> 6;
    const int wr = wid >> 1, wc = wid & 1;
    const int lo = lane & 15, hi = lane >> 4;
    const int row0 = blockIdx.y * 64, col0 = blockIdx.x * 128;
    const int r8 = lane >> 3, sp = lane & 7;
    const int srcoff = (sp ^ r8) << 3;
    f32x4 acc[2][4] = {};

    for (int kc = 0; kc < DIM; kc += 64) {
        __syncthreads();
#pragma unroll
        for (int it = 0; it < 2; it++) {
            int seg = it * 4 + wid;  // 8 segments x 8 rows
            int row = seg * 8 + r8;
            gld16(&A[(size_t)(row0 + row) * DIM + kc + srcoff], &As[seg * 512]);
        }
#pragma unroll
        for (int it = 0; it < 4; it++) {
            int seg = it * 4 + wid;  // 16 segments x 8 rows
            int row = seg * 8 + r8;
            gld16(&Bt[(size_t)(col0 + row) * DIM + kc + srcoff], &Bs[seg * 512]);
        }
        __syncthreads();
#pragma unroll
        for (int ks = 0; ks < 2; ks++) {
            short8 af[2], bfr[4];
#pragma unroll
            for (int m = 0; m < 2; m++) {
                int row = wr * 32 + m * 16 + lo;
                af[m] = *(const short8*)&As[row * 64 + (((ks * 4 + hi) ^ (row & 7)) << 3)];
            }
#pragma unroll
            for (int n = 0; n < 4; n++) {
                int row = wc * 64 + n * 16 + lo;
                bfr[n] = *(const short8*)&Bs[row * 64 + (((ks * 4 + hi) ^ (row & 7)) << 3)];
            }
#pragma unroll
            for (int m = 0; m < 2; m++)
#pragma unroll
                for (int n = 0; n < 4; n++)
                    acc[m][n] = __builtin_amdgcn_mfma_f32_16x16x32_bf16(af[m], bfr[n], acc[m][n], 0, 0, 0);
        }
    }

    float bb[4];
#pragma unroll
    for (int n = 0; n < 4; n++) bb[n] = bias[col0 + wc * 64 + n * 16 + lo];
#pragma unroll
    for (int m = 0; m < 2; m++)
#pragma unroll
        for (int n = 0; n < 4; n++)
#pragma unroll
            for (int r = 0; r < 4; r++) acc[m][n][r] += bb[n];

    __syncthreads();  // done with staging LDS
    float* tl = (float*)(lbuf + wid * 8192);  // wave-private [32][64] fp32
#pragma unroll
    for (int m = 0; m < 2; m++)
#pragma unroll
        for (int n = 0; n < 4; n++)
#pragma unroll
            for (int r = 0; r < 4; r++) {
                int row = m * 16 + hi * 4 + r;
                int col = n * 16 + lo;
                int cc = col >> 2;
                tl[row * 64 + ((cc ^ (row & 7)) << 2) + (col & 3)] = acc[m][n][r];
            }
#pragma unroll
    for (int j = 0; j < 8; j++) {
        int cid = j * 64 + lane;  // 512 16B chunks: row-major [32][16]
        int rowR = cid >> 4, cc = cid & 15;
        f32x4 v = *(const f32x4*)&tl[rowR * 64 + ((cc ^ (rowR & 7)) << 2)];
        int rg = row0 + wr * 32 + rowR;
        int cgl = col0 + wc * 64 + cc * 4;
        *(f32x4*)&outF[(size_t)rg * DIM + cgl] = v;
    }
}

// ---------------------------------------------------------------------------
// Causal flash attention, swapped-QK^T, exact fixed-shift exp2 softmax.
// (unchanged from R5 — est. ~15-20 us)
// ---------------------------------------------------------------------------
__global__ __launch_bounds__(512, 4) void attn(const ushortT* __restrict__ Q,
                                               const ushortT* __restrict__ K,
                                               const ushortT* __restrict__ VF,
                                               const float* __restrict__ scale,
                                               ushortT* __restrict__ ctx) {
    __shared__ __align__(16) ushortT Ks[64 * 64];
    __shared__ __align__(16) ushortT Ps[8 * 16 * 64];
    const int tid = threadIdx.x, lane = tid & 63, wid = tid >> 6;
    const int wg = wid & 3, sg = wid >> 2;
    const int bh = blockIdx.x, p = blockIdx.y;
    const int qt = sg ? p : 31 - p;
    const int kbmax = 31 - p;
    const size_t hb = (size_t)bh * SLEN * DPH;
    const int lo = lane & 15, hi = lane >> 4;
    const float mshift = fabsf(scale[0]) * LOG2E;

    short8 aq[2];
    {
        const int qrow = qt * 64 + wg * 16 + lo;
#pragma unroll
        for (int ks = 0; ks < 2; ks++)
            aq[ks] = *(const short8*)&Q[hb + (size_t)qrow * DPH + ks * 32 + 8 * hi];
    }

    const int srow = tid >> 3, sslot = tid & 7;
    const int sldsoff = srow * 64 + ((sslot ^ (srow & 7)) << 3);
    uint4 kr = *(const uint4*)&K[hb + (size_t)srow * DPH + sslot * 8];
    *(uint4*)&Ks[sldsoff] = kr;
    __syncthreads();

    f32x4 accd[4] = {};
    float lp = 0.f;

    for (int kb = 0; kb <= kbmax; kb++) {
        if (kb < kbmax)
            kr = *(const uint4*)&K[hb + (size_t)((kb + 1) * 64 + srow) * DPH + sslot * 8];

        if (kb <= qt) {
            short8 bv[8];
            const ushortT* vt = &VF[(((size_t)bh * 32 + kb) * 512 + lane) * 8];
#pragma unroll
            for (int c = 0; c < 8; c++) bv[c] = *(const short8*)&vt[(size_t)c * 512];

            f32x4 sf[4] = {};
#pragma unroll
            for (int ks = 0; ks < 2; ks++)
#pragma unroll
                for (int j = 0; j < 4; j++) {
                    int row = j * 16 + lo;
                    short8 bk = *(const short8*)&Ks[row * 64 + (((ks * 4 + hi) ^ (row & 7)) << 3)];
                    sf[j] = __builtin_amdgcn_mfma_f32_16x16x32_bf16(bk, aq[ks], sf[j], 0, 0, 0);
                }

            if (kb == qt) {
#pragma unroll
                for (int j = 0; j < 4; j++)
#pragma unroll
                    for (int r = 0; r < 4; r++)
                        if (j * 16 + 4 * hi + r > wg * 16 + lo) sf[j][r] = -INFINITY;
            }

#pragma unroll
            for (int j = 0; j < 4; j++) {
                s16x4 pk;
#pragma unroll
                for (int r = 0; r < 4; r++) {
                    float pv = __builtin_amdgcn_exp2f(sf[j][r] - mshift);
                    lp += pv;
                    pk[r] = (short)f2bf(pv);
                }
                int slot = (4 * j + hi) ^ (2 * (lo & 7));
                *(s16x4*)&Ps[wid * 1024 + lo * 64 + slot * 4] = pk;
            }

#pragma unroll
            for (int ks = 0; ks < 2; ks++) {
                int slot0 = (8 * ks + 2 * hi) ^ (2 * (lo & 7));
                short8 ap = *(const short8*)&Ps[wid * 1024 + lo * 64 + slot0 * 4];
#pragma unroll
                for (int jd = 0; jd < 4; jd++)
                    accd[jd] = __builtin_amdgcn_mfma_f32_16x16x32_bf16(ap, bv[jd * 2 + ks], accd[jd], 0, 0, 0);
            }
        }

        __syncthreads();
        if (kb < kbmax) {
            *(uint4*)&Ks[sldsoff] = kr;
            __syncthreads();
        }
    }

    lp += __shfl_xor(lp, 16);
    lp += __shfl_xor(lp, 32);

    const int b = bh >> 4, h = bh & 15;
#pragma unroll
    for (int r = 0; r < 4; r++) {
        float lr = __shfl(lp, (lane & 48) | (4 * hi + r));
        float inv = 1.0f / lr;
        int t = qt * 64 + wg * 16 + 4 * hi + r;
#pragma unroll
        for (int jd = 0; jd < 4; jd++) {
            int d = jd * 16 + lo;
            ctx[(size_t)(b * SLEN + t) * DIM + h * 64 + d] = f2bf(accd[jd][r] * inv);
        }
    }
}

// ---------------------------------------------------------------------------
// inputs: 0 x, 1 mask(unused), 2 Wq, 3 bq, 4 Wk, 5 bk, 6 Wv, 7 bv, 8 Wo,
// 9 bo, 10 attention_scale
// ---------------------------------------------------------------------------
extern "C" void kernel_launch(void* const* d_in, const int* in_sizes, int n_in,
                              void* d_out, int out_size, void* d_ws,
                              size_t ws_size, hipStream_t stream) {
    const float* x = (const float*)d_in[0];
    const float* Wq = (const float*)d_in[2];
    const float* bq = (const float*)d_in[3];
    const float* Wk = (const float*)d_in[4];
    const float* bk = (const float*)d_in[5];
    const float* Wv = (const float*)d_in[6];
    const float* bv = (const float*)d_in[7];
    const float* Wo = (const float*)d_in[8];
    const float* bo = (const float*)d_in[9];
    const float* ascale = (const float*)d_in[10];
    float* outF = (float*)d_out;

    unsigned char* ws = (unsigned char*)d_ws;
    const size_t MB = 1u << 20;
    ushortT* xb = (ushortT*)(ws);               // 8 MB
    ushortT* Wqkvt = (ushortT*)(ws + 8 * MB);   // 6 MB
    ushortT* Wot = (ushortT*)(ws + 14 * MB);    // 2 MB
    ushortT* Qb = (ushortT*)(ws + 16 * MB);     // 8 MB
    ushortT* Kb = (ushortT*)(ws + 24 * MB);     // 8 MB
    ushortT* VFb = (ushortT*)(ws + 32 * MB);    // 8 MB (written by gemm_qkv)
    ushortT* ctxb = (ushortT*)(ws + 40 * MB);   // 8 MB; total 48 MB

    cvt_x<<<NTOK * DIM / (8 * 256), 256, 0, stream>>>(x, xb);
    cvt_wt<<<dim3(16, 16, 4), 256, 0, stream>>>(Wq, Wk, Wv, Wo, Wqkvt,
                                                Wqkvt + (size_t)1024 * 1024,
                                                Wqkvt + (size_t)2048 * 1024, Wot);

    gemm_qkv<<<dim3(3 * DIM / 128, NTOK / 128), 256, 0, stream>>>(
        xb, Wqkvt, bq, bk, bv, ascale, Qb, Kb, VFb);

    attn<<<dim3(32, 16), 512, 0, stream>>>(Qb, Kb, VFb, ascale, ctxb);

    gemm_oproj<<<dim3(DIM / 128, NTOK / 64), 256, 0, stream>>>(ctxb, Wot, bo, outF);
}

// Round 7
// 106.754 us; speedup vs baseline: 15.2607x; 1.0473x over previous
//
#include <hip/hip_runtime.h>
#include <math.h>

#define NH 16
#define DPH 64
#define SLEN 2048
#define BSZ 2
#define DIM 1024
#define NTOK (BSZ * SLEN)
#define LOG2E 1.44269504088896f

typedef unsigned short ushortT;
typedef __attribute__((ext_vector_type(8))) short short8;
typedef __attribute__((ext_vector_type(4))) short s16x4;
typedef __attribute__((ext_vector_type(4))) float f32x4;

typedef __attribute__((address_space(1))) const unsigned int gu32c;
typedef __attribute__((address_space(3))) unsigned int lu32;

__device__ __forceinline__ void gld16(const void* g, void* l) {
    __builtin_amdgcn_global_load_lds((gu32c*)g, (lu32*)l, 16, 0, 0);
}

__device__ __forceinline__ ushortT f2bf(float f) {
    unsigned int u = __builtin_bit_cast(unsigned int, f);
    u = u + 0x7fffu + ((u >> 16) & 1u);  // RNE
    return (ushortT)(u >> 16);
}

// ---------------------------------------------------------------------------
// x (fp32) -> bf16, 8 elems/thread
// ---------------------------------------------------------------------------
__global__ __launch_bounds__(256) void cvt_x(const float* __restrict__ x,
                                             ushortT* __restrict__ xb) {
    size_t i = (size_t)blockIdx.x * 256 + threadIdx.x;
    float4 a = *(const float4*)&x[i * 8];
    float4 b = *(const float4*)&x[i * 8 + 4];
    short8 v;
    v[0] = (short)f2bf(a.x); v[1] = (short)f2bf(a.y);
    v[2] = (short)f2bf(a.z); v[3] = (short)f2bf(a.w);
    v[4] = (short)f2bf(b.x); v[5] = (short)f2bf(b.y);
    v[6] = (short)f2bf(b.z); v[7] = (short)f2bf(b.w);
    *(short8*)&xb[i * 8] = v;
}

// ---------------------------------------------------------------------------
// W[k][n] fp32 -> Wt[n][k] bf16 (transpose + convert), 64x64 tiles
// ---------------------------------------------------------------------------
__global__ __launch_bounds__(256) void cvt_wt(const float* __restrict__ W0, const float* __restrict__ W1,
                                              const float* __restrict__ W2, const float* __restrict__ W3,
                                              ushortT* __restrict__ T0, ushortT* __restrict__ T1,
                                              ushortT* __restrict__ T2, ushortT* __restrict__ T3) {
    const float* W = blockIdx.z == 0 ? W0 : blockIdx.z == 1 ? W1 : blockIdx.z == 2 ? W2 : W3;
    ushortT* T = blockIdx.z == 0 ? T0 : blockIdx.z == 1 ? T1 : blockIdx.z == 2 ? T2 : T3;
    __shared__ float tile[64][65];
    const int tid = threadIdx.x;
    const int kb = blockIdx.y * 64, nb = blockIdx.x * 64;
#pragma unroll
    for (int it = 0; it < 4; it++) {
        int chunk = it * 256 + tid;
        int r = chunk >> 4, c4 = (chunk & 15) * 4;
        *(float4*)&tile[r][c4] = *(const float4*)&W[(size_t)(kb + r) * DIM + nb + c4];
    }
    __syncthreads();
#pragma unroll
    for (int it = 0; it < 2; it++) {
        int chunk = it * 256 + tid;
        int n = chunk >> 3, k8 = (chunk & 7) * 8;
        short8 o;
#pragma unroll
        for (int j = 0; j < 8; j++) o[j] = (short)f2bf(tile[k8 + j][n]);
        *(short8*)&T[(size_t)(nb + n) * DIM + kb + k8] = o;
    }
}

// ---------------------------------------------------------------------------
// Fused QKV GEMM, 8-wave 256x256 tile, BK=64, 4-phase schedule with
// counted-load double-buffered gld16 staging (vmcnt(0) only at tile
// boundaries, where waited loads were issued 4 phases earlier).
// LDS per operand per buf: [2 ks][256 rows][32 bf16] (64B rows), swizzle:
// 16B-chunk bit1 ^= row bit3 (st_16x32). Epilogue: per-wave 128tok x 64d
// (one head): bias + fused L2 norm (Q,K) + LDS bounce -> coalesced stores;
// V waves emit VF MFMA-fragment layout directly.
// ---------------------------------------------------------------------------
__device__ __forceinline__ void stage_tile(const ushortT* __restrict__ A,
                                           const ushortT* __restrict__ Bt,
                                           ushortT* lds, int row0, int col0,
                                           int kc, int bb, int srow, int sphys) {
#pragma unroll
    for (int h = 0; h < 4; h++) {
        int rl = (h & 1) * 128 + srow;
        int lch = sphys ^ (((rl >> 3) & 1) << 1);
        const ushortT* g = (h < 2) ? &A[(size_t)(row0 + rl) * DIM + kc + lch * 8]
                                   : &Bt[(size_t)(col0 + rl) * DIM + kc + lch * 8];
        int lb = ((h < 2) ? 0 : 32768) + bb * 16384 + rl * 32 + sphys * 8;
        gld16(g, &lds[lb]);           // ks=0 half of the row
        gld16(g + 32, &lds[lb + 8192]);  // ks=1 half
    }
}

__global__ __launch_bounds__(512, 2) void gemm_qkv8(const ushortT* __restrict__ A,
                                                    const ushortT* __restrict__ Bt,
                                                    const float* __restrict__ bq,
                                                    const float* __restrict__ bk,
                                                    const float* __restrict__ bv,
                                                    const float* __restrict__ ascale,
                                                    ushortT* __restrict__ Qb,
                                                    ushortT* __restrict__ Kb,
                                                    ushortT* __restrict__ VF) {
    __shared__ __align__(16) ushortT lds[65536];  // 128 KiB: A bufs [0,32768), B bufs [32768,65536)
    const int tid = threadIdx.x;
    const int lane = tid & 63, wid = tid >> 6;
    const int wm = wid >> 2, wn = wid & 3;  // 2 x 4 waves
    const int lo = lane & 15, hi = lane >> 4;
    const int bid = blockIdx.x;
    const int swz = (bid & 7) * 24 + (bid >> 3);  // XCD-bijective (192 % 8 == 0)
    const int bx = swz % 12, by = swz / 12;
    const int row0 = by * 256, col0 = bx * 256;
    const int srow = tid >> 2, sphys = tid & 3;
    f32x4 acc[8][4] = {};

    stage_tile(A, Bt, lds, row0, col0, 0, 0, srow, sphys);

    for (int tt = 0; tt < 16; ++tt) {
        const int bb = tt & 1;
        const int abase = bb * 16384, bbase = 32768 + bb * 16384;
#pragma unroll
        for (int ph = 0; ph < 4; ++ph) {
            const int ks = ph & 1, mh = ph >> 1;
            if (ph == 0) {
                asm volatile("s_waitcnt vmcnt(0)" ::: "memory");
                asm volatile("s_barrier" ::: "memory");
            }
            short8 af[4], bfr[4];
#pragma unroll
            for (int mm = 0; mm < 4; mm++) {
                int row = wm * 128 + (mh * 4 + mm) * 16 + lo;
                int phys = hi ^ (((row >> 3) & 1) << 1);
                af[mm] = *(const short8*)&lds[abase + ks * 8192 + row * 32 + phys * 8];
            }
#pragma unroll
            for (int n = 0; n < 4; n++) {
                int row = wn * 64 + n * 16 + lo;
                int phys = hi ^ (((row >> 3) & 1) << 1);
                bfr[n] = *(const short8*)&lds[bbase + ks * 8192 + row * 32 + phys * 8];
            }
            if (ph == 0 && tt < 15)
                stage_tile(A, Bt, lds, row0, col0, (tt + 1) * 64, bb ^ 1, srow, sphys);
            __builtin_amdgcn_s_setprio(1);
#pragma unroll
            for (int mm = 0; mm < 4; mm++)
#pragma unroll
                for (int n = 0; n < 4; n++)
                    acc[mh * 4 + mm][n] = __builtin_amdgcn_mfma_f32_16x16x32_bf16(
                        af[mm], bfr[n], acc[mh * 4 + mm][n], 0, 0, 0);
            __builtin_amdgcn_s_setprio(0);
            asm volatile("s_barrier" ::: "memory");
        }
    }

    // ---- epilogue: wave tile = 128 tokens x 64 d (one head slab) ----
    const int cg = col0 + wn * 64;
    const int which = cg >> 10;  // 0=Q 1=K 2=V (block-uniform: col0 is 256-aligned)
    const int cwin = cg & 1023;
    const int h = cwin >> 6;
    const int t0g = row0 + wm * 128;
    const int b = t0g >> 11, tok0 = t0g & (SLEN - 1);
    const float* bias = which == 0 ? bq : which == 1 ? bk : bv;

    float bb4[4];
#pragma unroll
    for (int n = 0; n < 4; n++) bb4[n] = bias[cwin + n * 16 + lo];
#pragma unroll
    for (int m = 0; m < 8; m++)
#pragma unroll
        for (int n = 0; n < 4; n++)
#pragma unroll
            for (int r = 0; r < 4; r++) acc[m][n][r] += bb4[n];

    if (which < 2) {  // fused L2 norm over the 64-wide head row
        float asc = (which == 0) ? ascale[0] * LOG2E : 1.0f;
#pragma unroll
        for (int m = 0; m < 8; m++)
#pragma unroll
            for (int r = 0; r < 4; r++) {
                float ss = acc[m][0][r] * acc[m][0][r] + acc[m][1][r] * acc[m][1][r] +
                           acc[m][2][r] * acc[m][2][r] + acc[m][3][r] * acc[m][3][r];
#pragma unroll
                for (int o = 8; o > 0; o >>= 1) ss += __shfl_xor(ss, o);
                float sc = asc / fmaxf(sqrtf(ss), 1e-12f);
#pragma unroll
                for (int n = 0; n < 4; n++) acc[m][n][r] *= sc;
            }
    }

    // wave-private 16KB bounce region (LDS staging is dead after final barrier)
    ushortT* tl = &lds[wid * 8192];
    if (which < 2) {
        // row-consecutive readback: swizzle chunk c ^ (row & 7)
#pragma unroll
        for (int m = 0; m < 8; m++)
#pragma unroll
            for (int n = 0; n < 4; n++)
#pragma unroll
                for (int r = 0; r < 4; r++) {
                    int row = m * 16 + 4 * hi + r;
                    int c = n * 2 + (lo >> 3);
                    tl[row * 64 + ((c ^ (row & 7)) << 3) + (lo & 7)] = f2bf(acc[m][n][r]);
                }
        ushortT* op = which == 0 ? Qb : Kb;
        const size_t base = ((size_t)(b * NH + h) * SLEN + tok0) * DPH;
#pragma unroll
        for (int j = 0; j < 16; j++) {
            int cid = j * 64 + lane;  // 1024 16B chunks: row-major [128][8]
            int rowL = cid >> 3, c = cid & 7;
            uint4 v = *(const uint4*)&tl[rowL * 64 + ((c ^ (rowL & 7)) << 3)];
            *(uint4*)&op[base + (size_t)cid * 8] = v;
        }
    } else {
        // column-wise readback (keys-consecutive): swizzle c ^ ((row>>3)&7)
#pragma unroll
        for (int m = 0; m < 8; m++)
#pragma unroll
            for (int n = 0; n < 4; n++)
#pragma unroll
                for (int r = 0; r < 4; r++) {
                    int row = m * 16 + 4 * hi + r;
                    int c = n * 2 + (lo >> 3);
                    tl[row * 64 + ((c ^ ((row >> 3) & 7)) << 3) + (lo & 7)] = f2bf(acc[m][n][r]);
                }
        const int bh = b * NH + h;
        const int kt0 = tok0 >> 6;  // wave covers key-tiles kt0, kt0+1
#pragma unroll
        for (int i = 0; i < 16; i++) {
            int kk = i >> 3;      // key-tile half (64 tokens each)
            int c = i & 7;        // VF chunk: jd = c>>1, ks = c&1
            int jd = c >> 1, ks2 = c & 1;
            int colL = jd * 16 + lo;
            int c2 = colL >> 3;
            short8 v;
#pragma unroll
            for (int e = 0; e < 8; e++) {
                int rowL = kk * 64 + ks2 * 32 + 8 * hi + e;
                v[e] = (short)tl[rowL * 64 + ((c2 ^ ((rowL >> 3) & 7)) << 3) + (colL & 7)];
            }
            *(short8*)&VF[((size_t)bh * 32 + kt0 + kk) * 4096 + (size_t)(c * 64 + lane) * 8] = v;
        }
    }
}

// ---------------------------------------------------------------------------
// O-projection: out = ctx(4096,1024) @ Wo^T(1024,1024) + bo, fp32 out.
// 64x128 tile, BK=64 -> grid 8x64 = 512 blocks (2/CU).
// ---------------------------------------------------------------------------
__global__ __launch_bounds__(256) void gemm_oproj(const ushortT* __restrict__ A,
                                                  const ushortT* __restrict__ Bt,
                                                  const float* __restrict__ bias,
                                                  float* __restrict__ outF) {
    __shared__ __align__(16) unsigned char lbuf[32768];
    ushortT* As = (ushortT*)lbuf;             // [64][64] bf16, 8KB
    ushortT* Bs = (ushortT*)(lbuf + 8192);    // [128][64] bf16, 16KB
    const int tid = threadIdx.x;
    const int lane = tid & 63, wid = tid >> 6;
    const int wr = wid >> 1, wc = wid & 1;
    const int lo = lane & 15, hi = lane >> 4;
    const int row0 = blockIdx.y * 64, col0 = blockIdx.x * 128;
    const int r8 = lane >> 3, sp = lane & 7;
    const int srcoff = (sp ^ r8) << 3;
    f32x4 acc[2][4] = {};

    for (int kc = 0; kc < DIM; kc += 64) {
        __syncthreads();
#pragma unroll
        for (int it = 0; it < 2; it++) {
            int seg = it * 4 + wid;
            int row = seg * 8 + r8;
            gld16(&A[(size_t)(row0 + row) * DIM + kc + srcoff], &As[seg * 512]);
        }
#pragma unroll
        for (int it = 0; it < 4; it++) {
            int seg = it * 4 + wid;
            int row = seg * 8 + r8;
            gld16(&Bt[(size_t)(col0 + row) * DIM + kc + srcoff], &Bs[seg * 512]);
        }
        __syncthreads();
#pragma unroll
        for (int ks = 0; ks < 2; ks++) {
            short8 af[2], bfr[4];
#pragma unroll
            for (int m = 0; m < 2; m++) {
                int row = wr * 32 + m * 16 + lo;
                af[m] = *(const short8*)&As[row * 64 + (((ks * 4 + hi) ^ (row & 7)) << 3)];
            }
#pragma unroll
            for (int n = 0; n < 4; n++) {
                int row = wc * 64 + n * 16 + lo;
                bfr[n] = *(const short8*)&Bs[row * 64 + (((ks * 4 + hi) ^ (row & 7)) << 3)];
            }
#pragma unroll
            for (int m = 0; m < 2; m++)
#pragma unroll
                for (int n = 0; n < 4; n++)
                    acc[m][n] = __builtin_amdgcn_mfma_f32_16x16x32_bf16(af[m], bfr[n], acc[m][n], 0, 0, 0);
        }
    }

    float bb[4];
#pragma unroll
    for (int n = 0; n < 4; n++) bb[n] = bias[col0 + wc * 64 + n * 16 + lo];
#pragma unroll
    for (int m = 0; m < 2; m++)
#pragma unroll
        for (int n = 0; n < 4; n++)
#pragma unroll
            for (int r = 0; r < 4; r++) acc[m][n][r] += bb[n];

    __syncthreads();
    float* tl = (float*)(lbuf + wid * 8192);  // wave-private [32][64] fp32
#pragma unroll
    for (int m = 0; m < 2; m++)
#pragma unroll
        for (int n = 0; n < 4; n++)
#pragma unroll
            for (int r = 0; r < 4; r++) {
                int row = m * 16 + hi * 4 + r;
                int col = n * 16 + lo;
                int cc = col >> 2;
                tl[row * 64 + ((cc ^ (row & 7)) << 2) + (col & 3)] = acc[m][n][r];
            }
#pragma unroll
    for (int j = 0; j < 8; j++) {
        int cid = j * 64 + lane;
        int rowR = cid >> 4, cc = cid & 15;
        f32x4 v = *(const f32x4*)&tl[rowR * 64 + ((cc ^ (rowR & 7)) << 2)];
        int rg = row0 + wr * 32 + rowR;
        int cgl = col0 + wc * 64 + cc * 4;
        *(f32x4*)&outF[(size_t)rg * DIM + cgl] = v;
    }
}

// ---------------------------------------------------------------------------
// Causal flash attention, swapped-QK^T, exact fixed-shift exp2 softmax.
// (unchanged from R5/R6)
// ---------------------------------------------------------------------------
__global__ __launch_bounds__(512, 4) void attn(const ushortT* __restrict__ Q,
                                               const ushortT* __restrict__ K,
                                               const ushortT* __restrict__ VF,
                                               const float* __restrict__ scale,
                                               ushortT* __restrict__ ctx) {
    __shared__ __align__(16) ushortT Ks[64 * 64];
    __shared__ __align__(16) ushortT Ps[8 * 16 * 64];
    const int tid = threadIdx.x, lane = tid & 63, wid = tid >> 6;
    const int wg = wid & 3, sg = wid >> 2;
    const int bh = blockIdx.x, p = blockIdx.y;
    const int qt = sg ? p : 31 - p;
    const int kbmax = 31 - p;
    const size_t hb = (size_t)bh * SLEN * DPH;
    const int lo = lane & 15, hi = lane >> 4;
    const float mshift = fabsf(scale[0]) * LOG2E;

    short8 aq[2];
    {
        const int qrow = qt * 64 + wg * 16 + lo;
#pragma unroll
        for (int ks = 0; ks < 2; ks++)
            aq[ks] = *(const short8*)&Q[hb + (size_t)qrow * DPH + ks * 32 + 8 * hi];
    }

    const int srow = tid >> 3, sslot = tid & 7;
    const int sldsoff = srow * 64 + ((sslot ^ (srow & 7)) << 3);
    uint4 kr = *(const uint4*)&K[hb + (size_t)srow * DPH + sslot * 8];
    *(uint4*)&Ks[sldsoff] = kr;
    __syncthreads();

    f32x4 accd[4] = {};
    float lp = 0.f;

    for (int kb = 0; kb <= kbmax; kb++) {
        if (kb < kbmax)
            kr = *(const uint4*)&K[hb + (size_t)((kb + 1) * 64 + srow) * DPH + sslot * 8];

        if (kb <= qt) {
            short8 bv[8];
            const ushortT* vt = &VF[(((size_t)bh * 32 + kb) * 512 + lane) * 8];
#pragma unroll
            for (int c = 0; c < 8; c++) bv[c] = *(const short8*)&vt[(size_t)c * 512];

            f32x4 sf[4] = {};
#pragma unroll
            for (int ks = 0; ks < 2; ks++)
#pragma unroll
                for (int j = 0; j < 4; j++) {
                    int row = j * 16 + lo;
                    short8 bk = *(const short8*)&Ks[row * 64 + (((ks * 4 + hi) ^ (row & 7)) << 3)];
                    sf[j] = __builtin_amdgcn_mfma_f32_16x16x32_bf16(bk, aq[ks], sf[j], 0, 0, 0);
                }

            if (kb == qt) {
#pragma unroll
                for (int j = 0; j < 4; j++)
#pragma unroll
                    for (int r = 0; r < 4; r++)
                        if (j * 16 + 4 * hi + r > wg * 16 + lo) sf[j][r] = -INFINITY;
            }

#pragma unroll
            for (int j = 0; j < 4; j++) {
                s16x4 pk;
#pragma unroll
                for (int r = 0; r < 4; r++) {
                    float pv = __builtin_amdgcn_exp2f(sf[j][r] - mshift);
                    lp += pv;
                    pk[r] = (short)f2bf(pv);
                }
                int slot = (4 * j + hi) ^ (2 * (lo & 7));
                *(s16x4*)&Ps[wid * 1024 + lo * 64 + slot * 4] = pk;
            }

#pragma unroll
            for (int ks = 0; ks < 2; ks++) {
                int slot0 = (8 * ks + 2 * hi) ^ (2 * (lo & 7));
                short8 ap = *(const short8*)&Ps[wid * 1024 + lo * 64 + slot0 * 4];
#pragma unroll
                for (int jd = 0; jd < 4; jd++)
                    accd[jd] = __builtin_amdgcn_mfma_f32_16x16x32_bf16(ap, bv[jd * 2 + ks], accd[jd], 0, 0, 0);
            }
        }

        __syncthreads();
        if (kb < kbmax) {
            *(uint4*)&Ks[sldsoff] = kr;
            __syncthreads();
        }
    }

    lp += __shfl_xor(lp, 16);
    lp += __shfl_xor(lp, 32);

    const int b = bh >> 4, h = bh & 15;
#pragma unroll
    for (int r = 0; r < 4; r++) {
        float lr = __shfl(lp, (lane & 48) | (4 * hi + r));
        float inv = 1.0f / lr;
        int t = qt * 64 + wg * 16 + 4 * hi + r;
#pragma unroll
        for (int jd = 0; jd < 4; jd++) {
            int d = jd * 16 + lo;
            ctx[(size_t)(b * SLEN + t) * DIM + h * 64 + d] = f2bf(accd[jd][r] * inv);
        }
    }
}

// ---------------------------------------------------------------------------
// inputs: 0 x, 1 mask(unused), 2 Wq, 3 bq, 4 Wk, 5 bk, 6 Wv, 7 bv, 8 Wo,
// 9 bo, 10 attention_scale
// ---------------------------------------------------------------------------
extern "C" void kernel_launch(void* const* d_in, const int* in_sizes, int n_in,
                              void* d_out, int out_size, void* d_ws,
                              size_t ws_size, hipStream_t stream) {
    const float* x = (const float*)d_in[0];
    const float* Wq = (const float*)d_in[2];
    const float* bq = (const float*)d_in[3];
    const float* Wk = (const float*)d_in[4];
    const float* bk = (const float*)d_in[5];
    const float* Wv = (const float*)d_in[6];
    const float* bv = (const float*)d_in[7];
    const float* Wo = (const float*)d_in[8];
    const float* bo = (const float*)d_in[9];
    const float* ascale = (const float*)d_in[10];
    float* outF = (float*)d_out;

    unsigned char* ws = (unsigned char*)d_ws;
    const size_t MB = 1u << 20;
    ushortT* xb = (ushortT*)(ws);               // 8 MB
    ushortT* Wqkvt = (ushortT*)(ws + 8 * MB);   // 6 MB
    ushortT* Wot = (ushortT*)(ws + 14 * MB);    // 2 MB
    ushortT* Qb = (ushortT*)(ws + 16 * MB);     // 8 MB
    ushortT* Kb = (ushortT*)(ws + 24 * MB);     // 8 MB
    ushortT* VFb = (ushortT*)(ws + 32 * MB);    // 8 MB
    ushortT* ctxb = (ushortT*)(ws + 40 * MB);   // 8 MB; total 48 MB

    cvt_x<<<NTOK * DIM / (8 * 256), 256, 0, stream>>>(x, xb);
    cvt_wt<<<dim3(16, 16, 4), 256, 0, stream>>>(Wq, Wk, Wv, Wo, Wqkvt,
                                                Wqkvt + (size_t)1024 * 1024,
                                                Wqkvt + (size_t)2048 * 1024, Wot);

    gemm_qkv8<<<dim3(192), 512, 0, stream>>>(xb, Wqkvt, bq, bk, bv, ascale, Qb, Kb, VFb);

    attn<<<dim3(32, 16), 512, 0, stream>>>(Qb, Kb, VFb, ascale, ctxb);

    gemm_oproj<<<dim3(DIM / 128, NTOK / 64), 256, 0, stream>>>(ctxb, Wot, bo, outF);
}

// Round 8
// 102.258 us; speedup vs baseline: 15.9315x; 1.0440x over previous
//
#include <hip/hip_runtime.h>
#include <math.h>

#define NH 16
#define DPH 64
#define SLEN 2048
#define BSZ 2
#define DIM 1024
#define NTOK (BSZ * SLEN)
#define LOG2E 1.44269504088896f

typedef unsigned short ushortT;
typedef __attribute__((ext_vector_type(8))) short short8;
typedef __attribute__((ext_vector_type(4))) short s16x4;
typedef __attribute__((ext_vector_type(4))) float f32x4;

typedef __attribute__((address_space(1))) const unsigned int gu32c;
typedef __attribute__((address_space(3))) unsigned int lu32;

__device__ __forceinline__ void gld16(const void* g, void* l) {
    __builtin_amdgcn_global_load_lds((gu32c*)g, (lu32*)l, 16, 0, 0);
}

__device__ __forceinline__ ushortT f2bf(float f) {
    unsigned int u = __builtin_bit_cast(unsigned int, f);
    u = u + 0x7fffu + ((u >> 16) & 1u);  // RNE
    return (ushortT)(u >> 16);
}

// ---------------------------------------------------------------------------
// x (fp32) -> bf16, 8 elems/thread
// ---------------------------------------------------------------------------
__global__ __launch_bounds__(256) void cvt_x(const float* __restrict__ x,
                                             ushortT* __restrict__ xb) {
    size_t i = (size_t)blockIdx.x * 256 + threadIdx.x;
    float4 a = *(const float4*)&x[i * 8];
    float4 b = *(const float4*)&x[i * 8 + 4];
    short8 v;
    v[0] = (short)f2bf(a.x); v[1] = (short)f2bf(a.y);
    v[2] = (short)f2bf(a.z); v[3] = (short)f2bf(a.w);
    v[4] = (short)f2bf(b.x); v[5] = (short)f2bf(b.y);
    v[6] = (short)f2bf(b.z); v[7] = (short)f2bf(b.w);
    *(short8*)&xb[i * 8] = v;
}

// ---------------------------------------------------------------------------
// W[k][n] fp32 -> Wt[n][k] bf16 (transpose + convert), 64x64 tiles
// ---------------------------------------------------------------------------
__global__ __launch_bounds__(256) void cvt_wt(const float* __restrict__ W0, const float* __restrict__ W1,
                                              const float* __restrict__ W2, const float* __restrict__ W3,
                                              ushortT* __restrict__ T0, ushortT* __restrict__ T1,
                                              ushortT* __restrict__ T2, ushortT* __restrict__ T3) {
    const float* W = blockIdx.z == 0 ? W0 : blockIdx.z == 1 ? W1 : blockIdx.z == 2 ? W2 : W3;
    ushortT* T = blockIdx.z == 0 ? T0 : blockIdx.z == 1 ? T1 : blockIdx.z == 2 ? T2 : T3;
    __shared__ float tile[64][65];
    const int tid = threadIdx.x;
    const int kb = blockIdx.y * 64, nb = blockIdx.x * 64;
#pragma unroll
    for (int it = 0; it < 4; it++) {
        int chunk = it * 256 + tid;
        int r = chunk >> 4, c4 = (chunk & 15) * 4;
        *(float4*)&tile[r][c4] = *(const float4*)&W[(size_t)(kb + r) * DIM + nb + c4];
    }
    __syncthreads();
#pragma unroll
    for (int it = 0; it < 2; it++) {
        int chunk = it * 256 + tid;
        int n = chunk >> 3, k8 = (chunk & 7) * 8;
        short8 o;
#pragma unroll
        for (int j = 0; j < 8; j++) o[j] = (short)f2bf(tile[k8 + j][n]);
        *(short8*)&T[(size_t)(nb + n) * DIM + kb + k8] = o;
    }
}

// ---------------------------------------------------------------------------
// Fused QKV GEMM, 8-wave 256x256 tile, BK=64, counted-vmcnt half-buffer ring:
// operand slots [buf][khalf] = [256 rows][32 k] (16KB each; A at 0, B at 64KB).
// 8 phases per iteration (2 K-tiles); each phase stages ONE half (2 gld16/thr)
// and waits vmcnt(8) only at odd phases -> loads stay >=5 phases in flight.
// Frag-read swizzle: chunk ^= (row>>1)&3 (2-way, free); stage source
// inverse-swizzled, LDS dest linear (wave-uniform + lane*16).
// Epilogue: per-wave 128tok x 64d slab -> bias + fused L2 norm (Q,K) +
// LDS bounce -> coalesced stores; V waves emit VF fragment layout directly.
// ---------------------------------------------------------------------------
__global__ __launch_bounds__(512, 2) void gemm_qkv8(const ushortT* __restrict__ A,
                                                    const ushortT* __restrict__ Bt,
                                                    const float* __restrict__ bq,
                                                    const float* __restrict__ bk,
                                                    const float* __restrict__ bv,
                                                    const float* __restrict__ ascale,
                                                    ushortT* __restrict__ Qb,
                                                    ushortT* __restrict__ Kb,
                                                    ushortT* __restrict__ VF) {
    __shared__ __align__(16) ushortT lds[65536];  // 128 KiB
    const int tid = threadIdx.x;
    const int lane = tid & 63, wid = tid >> 6;
    const int wm = wid >> 2, wn = wid & 3;  // 2 x 4 waves
    const int lo = lane & 15, hi = lane >> 4;
    const int bid = blockIdx.x;
    const int swz = (bid & 7) * 24 + (bid >> 3);  // XCD-bijective (192 % 8 == 0)
    const int bx = swz % 12, by = swz / 12;
    const int row0 = by * 256, col0 = bx * 256;
    const int srow2 = tid >> 2, sc = tid & 3;
    f32x4 acc[8][4] = {};
    short8 af[4], bfr[4];

    auto stage = [&](int isA, int buf, int ksh, int kt) {
        const ushortT* g = isA ? A : Bt;
        int r0 = isA ? row0 : col0;
        int base = (isA ? 0 : 32768) + (buf * 2 + ksh) * 8192;
#pragma unroll
        for (int r = 0; r < 2; r++) {
            int rl = r * 128 + srow2;
            int gch = sc ^ ((rl >> 1) & 3);
            gld16(&g[(size_t)(r0 + rl) * DIM + kt * 64 + ksh * 32 + gch * 8],
                  &lds[base + r * 4096 + tid * 8]);
        }
    };
    auto loadA = [&](int buf, int ks, int mh) {
        int base = (buf * 2 + ks) * 8192;
#pragma unroll
        for (int mm = 0; mm < 4; mm++) {
            int row = wm * 128 + (mh * 4 + mm) * 16 + lo;
            af[mm] = *(const short8*)&lds[base + row * 32 + (hi ^ ((row >> 1) & 3)) * 8];
        }
    };
    auto loadB = [&](int buf, int ks) {
        int base = 32768 + (buf * 2 + ks) * 8192;
#pragma unroll
        for (int n = 0; n < 4; n++) {
            int row = wn * 64 + n * 16 + lo;
            bfr[n] = *(const short8*)&lds[base + row * 32 + (hi ^ ((row >> 1) & 3)) * 8];
        }
    };
    auto mfma16 = [&](int mh) {
        __builtin_amdgcn_s_setprio(1);
#pragma unroll
        for (int mm = 0; mm < 4; mm++)
#pragma unroll
            for (int n = 0; n < 4; n++)
                acc[mh * 4 + mm][n] = __builtin_amdgcn_mfma_f32_16x16x32_bf16(
                    af[mm], bfr[n], acc[mh * 4 + mm][n], 0, 0, 0);
        __builtin_amdgcn_s_setprio(0);
    };

    // prologue: fill buf0 (tile 0, both k-halves) + buf1 k0 (tile 1)
    stage(1, 0, 0, 0); stage(0, 0, 0, 0);
    stage(1, 0, 1, 0); stage(0, 0, 1, 0);
    stage(1, 1, 0, 1); stage(0, 1, 0, 1);

#pragma unroll 1
    for (int it = 0; it < 8; ++it) {
        const int o = it * 2 + 1;       // odd tile of this iteration
        const bool more = (it < 7);
        // ph1: even tile, ks0, mh0
        asm volatile("s_waitcnt vmcnt(8)" ::: "memory");
        asm volatile("s_barrier" ::: "memory");
        loadA(0, 0, 0); loadB(0, 0);
        stage(1, 1, 1, o);
        mfma16(0);
        // ph2: ks0, mh1 (reuse B frags)
        asm volatile("s_barrier" ::: "memory");
        loadA(0, 0, 1);
        stage(0, 1, 1, o);
        mfma16(1);
        // ph3: ks1, mh0
        asm volatile("s_waitcnt vmcnt(8)" ::: "memory");
        asm volatile("s_barrier" ::: "memory");
        loadA(0, 1, 0); loadB(0, 1);
        if (more) stage(1, 0, 0, o + 1);
        mfma16(0);
        // ph4: ks1, mh1
        asm volatile("s_barrier" ::: "memory");
        loadA(0, 1, 1);
        if (more) stage(0, 0, 0, o + 1);
        mfma16(1);
        // ph5: odd tile, ks0, mh0
        if (more) { asm volatile("s_waitcnt vmcnt(8)" ::: "memory"); }
        else      { asm volatile("s_waitcnt vmcnt(4)" ::: "memory"); }
        asm volatile("s_barrier" ::: "memory");
        loadA(1, 0, 0); loadB(1, 0);
        if (more) stage(1, 0, 1, o + 1);
        mfma16(0);
        // ph6
        asm volatile("s_barrier" ::: "memory");
        loadA(1, 0, 1);
        if (more) stage(0, 0, 1, o + 1);
        mfma16(1);
        // ph7: ks1, mh0
        if (more) { asm volatile("s_waitcnt vmcnt(8)" ::: "memory"); }
        else      { asm volatile("s_waitcnt vmcnt(0)" ::: "memory"); }
        asm volatile("s_barrier" ::: "memory");
        loadA(1, 1, 0); loadB(1, 1);
        if (more) stage(1, 1, 0, o + 2);
        mfma16(0);
        // ph8
        asm volatile("s_barrier" ::: "memory");
        loadA(1, 1, 1);
        if (more) stage(0, 1, 0, o + 2);
        mfma16(1);
    }
    __syncthreads();  // all K-loop LDS reads done; staging LDS now dead

    // ---- epilogue: wave tile = 128 tokens x 64 d (one head slab) ----
    const int cg = col0 + wn * 64;
    const int which = cg >> 10;  // 0=Q 1=K 2=V (block-uniform)
    const int cwin = cg & 1023;
    const int h = cwin >> 6;
    const int t0g = row0 + wm * 128;
    const int b = t0g >> 11, tok0 = t0g & (SLEN - 1);
    const float* bias = which == 0 ? bq : which == 1 ? bk : bv;

    float bb4[4];
#pragma unroll
    for (int n = 0; n < 4; n++) bb4[n] = bias[cwin + n * 16 + lo];
#pragma unroll
    for (int m = 0; m < 8; m++)
#pragma unroll
        for (int n = 0; n < 4; n++)
#pragma unroll
            for (int r = 0; r < 4; r++) acc[m][n][r] += bb4[n];

    if (which < 2) {  // fused L2 norm over the 64-wide head row
        float asc = (which == 0) ? ascale[0] * LOG2E : 1.0f;
#pragma unroll
        for (int m = 0; m < 8; m++)
#pragma unroll
            for (int r = 0; r < 4; r++) {
                float ss = acc[m][0][r] * acc[m][0][r] + acc[m][1][r] * acc[m][1][r] +
                           acc[m][2][r] * acc[m][2][r] + acc[m][3][r] * acc[m][3][r];
#pragma unroll
                for (int o = 8; o > 0; o >>= 1) ss += __shfl_xor(ss, o);
                float sc2 = asc / fmaxf(sqrtf(ss), 1e-12f);
#pragma unroll
                for (int n = 0; n < 4; n++) acc[m][n][r] *= sc2;
            }
    }

    // wave-private 16KB bounce region
    ushortT* tl = &lds[wid * 8192];
    if (which < 2) {
        // row-consecutive readback: swizzle chunk c ^ (row & 7)
#pragma unroll
        for (int m = 0; m < 8; m++)
#pragma unroll
            for (int n = 0; n < 4; n++)
#pragma unroll
                for (int r = 0; r < 4; r++) {
                    int row = m * 16 + 4 * hi + r;
                    int c = n * 2 + (lo >> 3);
                    tl[row * 64 + ((c ^ (row & 7)) << 3) + (lo & 7)] = f2bf(acc[m][n][r]);
                }
        ushortT* op = which == 0 ? Qb : Kb;
        const size_t base = ((size_t)(b * NH + h) * SLEN + tok0) * DPH;
#pragma unroll
        for (int j = 0; j < 16; j++) {
            int cid = j * 64 + lane;  // 1024 16B chunks: row-major [128][8]
            int rowL = cid >> 3, c = cid & 7;
            uint4 v = *(const uint4*)&tl[rowL * 64 + ((c ^ (rowL & 7)) << 3)];
            *(uint4*)&op[base + (size_t)cid * 8] = v;
        }
    } else {
        // column-wise readback (keys-consecutive): swizzle c ^ ((row>>3)&7)
#pragma unroll
        for (int m = 0; m < 8; m++)
#pragma unroll
            for (int n = 0; n < 4; n++)
#pragma unroll
                for (int r = 0; r < 4; r++) {
                    int row = m * 16 + 4 * hi + r;
                    int c = n * 2 + (lo >> 3);
                    tl[row * 64 + ((c ^ ((row >> 3) & 7)) << 3) + (lo & 7)] = f2bf(acc[m][n][r]);
                }
        const int bh = b * NH + h;
        const int kt0 = tok0 >> 6;  // wave covers key-tiles kt0, kt0+1
#pragma unroll
        for (int i = 0; i < 16; i++) {
            int kk = i >> 3;
            int c = i & 7;  // VF chunk: jd = c>>1, ks = c&1
            int jd = c >> 1, ks2 = c & 1;
            int colL = jd * 16 + lo;
            int c2 = colL >> 3;
            short8 v;
#pragma unroll
            for (int e = 0; e < 8; e++) {
                int rowL = kk * 64 + ks2 * 32 + 8 * hi + e;
                v[e] = (short)tl[rowL * 64 + ((c2 ^ ((rowL >> 3) & 7)) << 3) + (colL & 7)];
            }
            *(short8*)&VF[((size_t)bh * 32 + kt0 + kk) * 4096 + (size_t)(c * 64 + lane) * 8] = v;
        }
    }
}

// ---------------------------------------------------------------------------
// O-projection: out = ctx(4096,1024) @ Wo^T(1024,1024) + bo, fp32 out.
// 64x128 tile, BK=64 -> grid 8x64 = 512 blocks (2/CU).
// ---------------------------------------------------------------------------
__global__ __launch_bounds__(256) void gemm_oproj(const ushortT* __restrict__ A,
                                                  const ushortT* __restrict__ Bt,
                                                  const float* __restrict__ bias,
                                                  float* __restrict__ outF) {
    __shared__ __align__(16) unsigned char lbuf[32768];
    ushortT* As = (ushortT*)lbuf;             // [64][64] bf16, 8KB
    ushortT* Bs = (ushortT*)(lbuf + 8192);    // [128][64] bf16, 16KB
    const int tid = threadIdx.x;
    const int lane = tid & 63, wid = tid >> 6;
    const int wr = wid >> 1, wc = wid & 1;
    const int lo = lane & 15, hi = lane >> 4;
    const int row0 = blockIdx.y * 64, col0 = blockIdx.x * 128;
    const int r8 = lane >> 3, sp = lane & 7;
    const int srcoff = (sp ^ r8) << 3;
    f32x4 acc[2][4] = {};

    for (int kc = 0; kc < DIM; kc += 64) {
        __syncthreads();
#pragma unroll
        for (int it = 0; it < 2; it++) {
            int seg = it * 4 + wid;
            int row = seg * 8 + r8;
            gld16(&A[(size_t)(row0 + row) * DIM + kc + srcoff], &As[seg * 512]);
        }
#pragma unroll
        for (int it = 0; it < 4; it++) {
            int seg = it * 4 + wid;
            int row = seg * 8 + r8;
            gld16(&Bt[(size_t)(col0 + row) * DIM + kc + srcoff], &Bs[seg * 512]);
        }
        __syncthreads();
#pragma unroll
        for (int ks = 0; ks < 2; ks++) {
            short8 af[2], bfr[4];
#pragma unroll
            for (int m = 0; m < 2; m++) {
                int row = wr * 32 + m * 16 + lo;
                af[m] = *(const short8*)&As[row * 64 + (((ks * 4 + hi) ^ (row & 7)) << 3)];
            }
#pragma unroll
            for (int n = 0; n < 4; n++) {
                int row = wc * 64 + n * 16 + lo;
                bfr[n] = *(const short8*)&Bs[row * 64 + (((ks * 4 + hi) ^ (row & 7)) << 3)];
            }
#pragma unroll
            for (int m = 0; m < 2; m++)
#pragma unroll
                for (int n = 0; n < 4; n++)
                    acc[m][n] = __builtin_amdgcn_mfma_f32_16x16x32_bf16(af[m], bfr[n], acc[m][n], 0, 0, 0);
        }
    }

    float bb[4];
#pragma unroll
    for (int n = 0; n < 4; n++) bb[n] = bias[col0 + wc * 64 + n * 16 + lo];
#pragma unroll
    for (int m = 0; m < 2; m++)
#pragma unroll
        for (int n = 0; n < 4; n++)
#pragma unroll
            for (int r = 0; r < 4; r++) acc[m][n][r] += bb[n];

    __syncthreads();
    float* tl = (float*)(lbuf + wid * 8192);  // wave-private [32][64] fp32
#pragma unroll
    for (int m = 0; m < 2; m++)
#pragma unroll
        for (int n = 0; n < 4; n++)
#pragma unroll
            for (int r = 0; r < 4; r++) {
                int row = m * 16 + hi * 4 + r;
                int col = n * 16 + lo;
                int cc = col >> 2;
                tl[row * 64 + ((cc ^ (row & 7)) << 2) + (col & 3)] = acc[m][n][r];
            }
#pragma unroll
    for (int j = 0; j < 8; j++) {
        int cid = j * 64 + lane;
        int rowR = cid >> 4, cc = cid & 15;
        f32x4 v = *(const f32x4*)&tl[rowR * 64 + ((cc ^ (rowR & 7)) << 2)];
        int rg = row0 + wr * 32 + rowR;
        int cgl = col0 + wc * 64 + cc * 4;
        *(f32x4*)&outF[(size_t)rg * DIM + cgl] = v;
    }
}

// ---------------------------------------------------------------------------
// Causal flash attention, swapped-QK^T, exact fixed-shift exp2 softmax.
// (unchanged from R5-R7)
// ---------------------------------------------------------------------------
__global__ __launch_bounds__(512, 4) void attn(const ushortT* __restrict__ Q,
                                               const ushortT* __restrict__ K,
                                               const ushortT* __restrict__ VF,
                                               const float* __restrict__ scale,
                                               ushortT* __restrict__ ctx) {
    __shared__ __align__(16) ushortT Ks[64 * 64];
    __shared__ __align__(16) ushortT Ps[8 * 16 * 64];
    const int tid = threadIdx.x, lane = tid & 63, wid = tid >> 6;
    const int wg = wid & 3, sg = wid >> 2;
    const int bh = blockIdx.x, p = blockIdx.y;
    const int qt = sg ? p : 31 - p;
    const int kbmax = 31 - p;
    const size_t hb = (size_t)bh * SLEN * DPH;
    const int lo = lane & 15, hi = lane >> 4;
    const float mshift = fabsf(scale[0]) * LOG2E;

    short8 aq[2];
    {
        const int qrow = qt * 64 + wg * 16 + lo;
#pragma unroll
        for (int ks = 0; ks < 2; ks++)
            aq[ks] = *(const short8*)&Q[hb + (size_t)qrow * DPH + ks * 32 + 8 * hi];
    }

    const int srow = tid >> 3, sslot = tid & 7;
    const int sldsoff = srow * 64 + ((sslot ^ (srow & 7)) << 3);
    uint4 kr = *(const uint4*)&K[hb + (size_t)srow * DPH + sslot * 8];
    *(uint4*)&Ks[sldsoff] = kr;
    __syncthreads();

    f32x4 accd[4] = {};
    float lp = 0.f;

    for (int kb = 0; kb <= kbmax; kb++) {
        if (kb < kbmax)
            kr = *(const uint4*)&K[hb + (size_t)((kb + 1) * 64 + srow) * DPH + sslot * 8];

        if (kb <= qt) {
            short8 bv[8];
            const ushortT* vt = &VF[(((size_t)bh * 32 + kb) * 512 + lane) * 8];
#pragma unroll
            for (int c = 0; c < 8; c++) bv[c] = *(const short8*)&vt[(size_t)c * 512];

            f32x4 sf[4] = {};
#pragma unroll
            for (int ks = 0; ks < 2; ks++)
#pragma unroll
                for (int j = 0; j < 4; j++) {
                    int row = j * 16 + lo;
                    short8 bk = *(const short8*)&Ks[row * 64 + (((ks * 4 + hi) ^ (row & 7)) << 3)];
                    sf[j] = __builtin_amdgcn_mfma_f32_16x16x32_bf16(bk, aq[ks], sf[j], 0, 0, 0);
                }

            if (kb == qt) {
#pragma unroll
                for (int j = 0; j < 4; j++)
#pragma unroll
                    for (int r = 0; r < 4; r++)
                        if (j * 16 + 4 * hi + r > wg * 16 + lo) sf[j][r] = -INFINITY;
            }

#pragma unroll
            for (int j = 0; j < 4; j++) {
                s16x4 pk;
#pragma unroll
                for (int r = 0; r < 4; r++) {
                    float pv = __builtin_amdgcn_exp2f(sf[j][r] - mshift);
                    lp += pv;
                    pk[r] = (short)f2bf(pv);
                }
                int slot = (4 * j + hi) ^ (2 * (lo & 7));
                *(s16x4*)&Ps[wid * 1024 + lo * 64 + slot * 4] = pk;
            }

#pragma unroll
            for (int ks = 0; ks < 2; ks++) {
                int slot0 = (8 * ks + 2 * hi) ^ (2 * (lo & 7));
                short8 ap = *(const short8*)&Ps[wid * 1024 + lo * 64 + slot0 * 4];
#pragma unroll
                for (int jd = 0; jd < 4; jd++)
                    accd[jd] = __builtin_amdgcn_mfma_f32_16x16x32_bf16(ap, bv[jd * 2 + ks], accd[jd], 0, 0, 0);
            }
        }

        __syncthreads();
        if (kb < kbmax) {
            *(uint4*)&Ks[sldsoff] = kr;
            __syncthreads();
        }
    }

    lp += __shfl_xor(lp, 16);
    lp += __shfl_xor(lp, 32);

    const int b = bh >> 4, h = bh & 15;
#pragma unroll
    for (int r = 0; r < 4; r++) {
        float lr = __shfl(lp, (lane & 48) | (4 * hi + r));
        float inv = 1.0f / lr;
        int t = qt * 64 + wg * 16 + 4 * hi + r;
#pragma unroll
        for (int jd = 0; jd < 4; jd++) {
            int d = jd * 16 + lo;
            ctx[(size_t)(b * SLEN + t) * DIM + h * 64 + d] = f2bf(accd[jd][r] * inv);
        }
    }
}

// ---------------------------------------------------------------------------
// inputs: 0 x, 1 mask(unused), 2 Wq, 3 bq, 4 Wk, 5 bk, 6 Wv, 7 bv, 8 Wo,
// 9 bo, 10 attention_scale
// ---------------------------------------------------------------------------
extern "C" void kernel_launch(void* const* d_in, const int* in_sizes, int n_in,
                              void* d_out, int out_size, void* d_ws,
                              size_t ws_size, hipStream_t stream) {
    const float* x = (const float*)d_in[0];
    const float* Wq = (const float*)d_in[2];
    const float* bq = (const float*)d_in[3];
    const float* Wk = (const float*)d_in[4];
    const float* bk = (const float*)d_in[5];
    const float* Wv = (const float*)d_in[6];
    const float* bv = (const float*)d_in[7];
    const float* Wo = (const float*)d_in[8];
    const float* bo = (const float*)d_in[9];
    const float* ascale = (const float*)d_in[10];
    float* outF = (float*)d_out;

    unsigned char* ws = (unsigned char*)d_ws;
    const size_t MB = 1u << 20;
    ushortT* xb = (ushortT*)(ws);               // 8 MB
    ushortT* Wqkvt = (ushortT*)(ws + 8 * MB);   // 6 MB
    ushortT* Wot = (ushortT*)(ws + 14 * MB);    // 2 MB
    ushortT* Qb = (ushortT*)(ws + 16 * MB);     // 8 MB
    ushortT* Kb = (ushortT*)(ws + 24 * MB);     // 8 MB
    ushortT* VFb = (ushortT*)(ws + 32 * MB);    // 8 MB
    ushortT* ctxb = (ushortT*)(ws + 40 * MB);   // 8 MB; total 48 MB

    cvt_x<<<NTOK * DIM / (8 * 256), 256, 0, stream>>>(x, xb);
    cvt_wt<<<dim3(16, 16, 4), 256, 0, stream>>>(Wq, Wk, Wv, Wo, Wqkvt,
                                                Wqkvt + (size_t)1024 * 1024,
                                                Wqkvt + (size_t)2048 * 1024, Wot);

    gemm_qkv8<<<dim3(192), 512, 0, stream>>>(xb, Wqkvt, bq, bk, bv, ascale, Qb, Kb, VFb);

    attn<<<dim3(32, 16), 512, 0, stream>>>(Qb, Kb, VFb, ascale, ctxb);

    gemm_oproj<<<dim3(DIM / 128, NTOK / 64), 256, 0, stream>>>(ctxb, Wot, bo, outF);
}